// Round 6
// baseline (891.391 us; speedup 1.0000x reference)
//
#include <hip/hip_runtime.h>
#include <math.h>
#include <stdint.h>

#define N_NODES 100000
#define N_EDGES 1000000
#define F_IN    128
#define ED_DIM  16
#define H_HEADS 5
#define C_CH    16
#define HC      80
#define NEG_SLOPE 0.2f

#define SCAN_B 256
#define SCAN_G ((N_NODES + SCAN_B - 1) / SCAN_B)   // 391
#define DBIN 64
#define EPAD 16  // padding entries on src_s/perm; 16 zeroed pad rows on eattr_h

typedef _Float16 h2 __attribute__((ext_vector_type(2)));

#if __has_builtin(__builtin_amdgcn_fdot2)
#define FDOT2(a, b, c) __builtin_amdgcn_fdot2((a), (b), (c), false)
#else
__device__ __forceinline__ float FDOT2(h2 a, h2 b, float c) {
    return (float)a.x * (float)b.x + (float)a.y * (float)b.y + c;
}
#endif

// cvt_pkrtz returns a __fp16-vector on this clang; bit_cast to our h2
#define PKH2(x, y) __builtin_bit_cast(h2, __builtin_amdgcn_cvt_pkrtz((x), (y)))

// ================= CSR build (graph is static across layers) =================

__global__ void k_hist(const int* __restrict__ dst, int* __restrict__ count) {
    const int e = blockIdx.x * 256 + threadIdx.x;
    if (e < N_EDGES) atomicAdd(count + dst[e], 1);
}

__global__ __launch_bounds__(SCAN_B) void k_part(const int* __restrict__ count,
                                                 int* __restrict__ partial) {
    const int i = blockIdx.x * SCAN_B + threadIdx.x;
    int v = (i < N_NODES) ? count[i] : 0;
    const int lane = threadIdx.x & 63;
    const int w    = threadIdx.x >> 6;
    __shared__ int ws[SCAN_B / 64];
    #pragma unroll
    for (int o = 32; o > 0; o >>= 1) v += __shfl_down(v, o, 64);
    if (lane == 0) ws[w] = v;
    __syncthreads();
    if (threadIdx.x == 0) {
        int s = 0;
        #pragma unroll
        for (int k = 0; k < SCAN_B / 64; ++k) s += ws[k];
        partial[blockIdx.x] = s;
    }
}

__global__ __launch_bounds__(512) void k_scanp(const int* __restrict__ partial,
                                               int* __restrict__ blockoff,
                                               int* __restrict__ rowstart) {
    __shared__ int s[512];
    const int t = threadIdx.x;
    int v = (t < SCAN_G) ? partial[t] : 0;
    s[t] = v;
    __syncthreads();
    for (int o = 1; o < 512; o <<= 1) {
        int u = (t >= o) ? s[t - o] : 0;
        __syncthreads();
        s[t] += u;
        __syncthreads();
    }
    if (t < SCAN_G) blockoff[t] = (t == 0) ? 0 : s[t - 1];
    if (t == 0) rowstart[N_NODES] = s[511];
}

// scan-apply + degree histogram fused (same node-domain pass)
__global__ __launch_bounds__(SCAN_B) void k_apply(const int* __restrict__ count,
                                                  const int* __restrict__ blockoff,
                                                  int* __restrict__ rowstart,
                                                  int* __restrict__ dhist) {
    __shared__ int s[SCAN_B];
    __shared__ int lh[DBIN];
    const int i = blockIdx.x * SCAN_B + threadIdx.x;
    const int t = threadIdx.x;
    const int v = (i < N_NODES) ? count[i] : 0;
    s[t] = v;
    if (t < DBIN) lh[t] = 0;
    __syncthreads();
    for (int o = 1; o < SCAN_B; o <<= 1) {
        int u = (t >= o) ? s[t - o] : 0;
        __syncthreads();
        s[t] += u;
        __syncthreads();
    }
    if (i < N_NODES) {
        rowstart[i] = blockoff[blockIdx.x] + (s[t] - v);
        atomicAdd(&lh[min(v, DBIN - 1)], 1);
    }
    __syncthreads();
    if (t < DBIN && lh[t] > 0) atomicAdd(dhist + t, lh[t]);
}

// place edge into CSR slot; src_s stores src*HC (pre-scaled for the hot loop);
// if COPY, also convert+copy the eattr row into CSR order as 16 f16 (32B),
// packed as 8 half2 words. Pad rows (N_EDGES..N_EDGES+EPAD) are zeroed so
// prefetch overshoot reads zeros (tail is predicated off; garbage never used).
template<bool COPY>
__global__ void k_place(const int* __restrict__ src, const int* __restrict__ dst,
                        const int* __restrict__ rowstart, int* __restrict__ cursor,
                        int* __restrict__ perm, int* __restrict__ src_s,
                        const float* __restrict__ eattr, int* __restrict__ eattr_h) {
    const int e = blockIdx.x * 256 + threadIdx.x;
    if (e >= N_EDGES) return;
    const int d = dst[e];
    const int pos = rowstart[d] + atomicAdd(cursor + d, 1);
    src_s[pos] = src[e] * HC;
    if (COPY) {
        const float4* s4 = (const float4*)(eattr + (size_t)e * ED_DIM);
        const float4 r0 = s4[0], r1 = s4[1], r2 = s4[2], r3 = s4[3];
        int4* d4 = (int4*)(eattr_h + (size_t)pos * 8);
        d4[0] = make_int4(__builtin_bit_cast(int, PKH2(r0.x, r0.y)),
                          __builtin_bit_cast(int, PKH2(r0.z, r0.w)),
                          __builtin_bit_cast(int, PKH2(r1.x, r1.y)),
                          __builtin_bit_cast(int, PKH2(r1.z, r1.w)));
        d4[1] = make_int4(__builtin_bit_cast(int, PKH2(r2.x, r2.y)),
                          __builtin_bit_cast(int, PKH2(r2.z, r2.w)),
                          __builtin_bit_cast(int, PKH2(r3.x, r3.y)),
                          __builtin_bit_cast(int, PKH2(r3.z, r3.w)));
        if (e < EPAD) {   // zero pad row N_EDGES+e (never hit by the scatter)
            int4* p4 = (int4*)(eattr_h + (size_t)(N_EDGES + e) * 8);
            p4[0] = make_int4(0, 0, 0, 0);
            p4[1] = make_int4(0, 0, 0, 0);
        }
    } else {
        perm[pos] = e;
    }
}

// also zeroes the perm/src_s padding (ws is re-poisoned before every launch)
__global__ void k_degoff(const int* __restrict__ dhist, int* __restrict__ dcur,
                         int* __restrict__ perm, int* __restrict__ src_s) {
    if (threadIdx.x == 0) {
        int off = 0;
        for (int b = DBIN - 1; b >= 0; --b) { dcur[b] = off; off += dhist[b]; }
        for (int i = 0; i < EPAD; ++i) {
            perm[N_EDGES + i]  = 0;
            src_s[N_EDGES + i] = 0;
        }
    }
}

__global__ __launch_bounds__(256) void k_degplace(const int* __restrict__ cnt,
                                                  int* __restrict__ dcur,
                                                  int* __restrict__ nodeord) {
    __shared__ int lh[DBIN];
    __shared__ int base[DBIN];
    const int t = threadIdx.x;
    if (t < DBIN) lh[t] = 0;
    __syncthreads();
    const int n = blockIdx.x * 256 + t;
    int b = 0, r = 0;
    if (n < N_NODES) {
        b = min(cnt[n], DBIN - 1);
        r = atomicAdd(&lh[b], 1);
    }
    __syncthreads();
    if (t < DBIN && lh[t] > 0) base[t] = atomicAdd(dcur + t, lh[t]);
    __syncthreads();
    if (n < N_NODES) nodeord[base[b] + r] = n;
}

// ====== fused dual node transform: xl = A@WL^T+bL, xr = A@WR^T+bR ============
template<int DIN>
__global__ __launch_bounds__(320) void k_xform2(
    const float* __restrict__ A,
    const float* __restrict__ WL, const float* __restrict__ bL,
    const float* __restrict__ WR, const float* __restrict__ bR,
    float* __restrict__ outL, float* __restrict__ outR, int nn) {
    __shared__ float As[16][68];
    __shared__ float WsL[16][80];
    __shared__ float WsR[16][80];
    const int t  = threadIdx.x;
    const int n0 = blockIdx.x * 64;
    const int tn = (t & 15) * 4;
    const int tj = (t >> 4) * 4;
    float4 accL[4], accR[4];
    #pragma unroll
    for (int u = 0; u < 4; ++u) {
        accL[u] = make_float4(0.f, 0.f, 0.f, 0.f);
        accR[u] = make_float4(0.f, 0.f, 0.f, 0.f);
    }

    for (int k0 = 0; k0 < DIN; k0 += 16) {
        __syncthreads();
        for (int i = t; i < 64*16; i += 320) {
            int nl = i >> 4, kk = i & 15;
            int n = n0 + nl;
            As[kk][nl] = (n < nn) ? A[(size_t)n*DIN + k0 + kk] : 0.f;
        }
        for (int i = t; i < 80*16; i += 320) {
            int jj = i >> 4, kk = i & 15;
            WsL[kk][jj] = WL[(size_t)jj*DIN + k0 + kk];
            WsR[kk][jj] = WR[(size_t)jj*DIN + k0 + kk];
        }
        __syncthreads();
        #pragma unroll
        for (int k = 0; k < 16; ++k) {
            const float4 av = *(const float4*)&As[k][tn];
            const float4 wl = *(const float4*)&WsL[k][tj];
            const float4 wr = *(const float4*)&WsR[k][tj];
            accL[0].x += av.x*wl.x; accL[0].y += av.x*wl.y; accL[0].z += av.x*wl.z; accL[0].w += av.x*wl.w;
            accL[1].x += av.y*wl.x; accL[1].y += av.y*wl.y; accL[1].z += av.y*wl.z; accL[1].w += av.y*wl.w;
            accL[2].x += av.z*wl.x; accL[2].y += av.z*wl.y; accL[2].z += av.z*wl.z; accL[2].w += av.z*wl.w;
            accL[3].x += av.w*wl.x; accL[3].y += av.w*wl.y; accL[3].z += av.w*wl.z; accL[3].w += av.w*wl.w;
            accR[0].x += av.x*wr.x; accR[0].y += av.x*wr.y; accR[0].z += av.x*wr.z; accR[0].w += av.x*wr.w;
            accR[1].x += av.y*wr.x; accR[1].y += av.y*wr.y; accR[1].z += av.y*wr.z; accR[1].w += av.y*wr.w;
            accR[2].x += av.z*wr.x; accR[2].y += av.z*wr.y; accR[2].z += av.z*wr.z; accR[2].w += av.z*wr.w;
            accR[3].x += av.w*wr.x; accR[3].y += av.w*wr.y; accR[3].z += av.w*wr.z; accR[3].w += av.w*wr.w;
        }
    }
    const float4 bvL = *(const float4*)(bL + tj);
    const float4 bvR = *(const float4*)(bR + tj);
    #pragma unroll
    for (int u = 0; u < 4; ++u) {
        int n = n0 + tn + u;
        if (n < nn) {
            float4 o;
            o.x = accL[u].x + bvL.x; o.y = accL[u].y + bvL.y;
            o.z = accL[u].z + bvL.z; o.w = accL[u].w + bvL.w;
            *(float4*)(outL + (size_t)n*HC + tj) = o;
            o.x = accR[u].x + bvR.x; o.y = accR[u].y + bvR.y;
            o.z = accR[u].z + bvR.z; o.w = accR[u].w + bvR.w;
            *(float4*)(outR + (size_t)n*HC + tj) = o;
        }
    }
}

// cross-lane helpers.
// BCH: compile-time ds_swizzle broadcast of a half2 word (DS pipe):
//   imm = (j<<5)|0x10 -> lane i reads lane (i&0x10)|j, i.e. each 16-lane row
//   gets pair j held by its own lane j. j in 0..7 covers the 16 f16 values.
#define BCH(bits, j) __builtin_bit_cast(h2, \
    __builtin_amdgcn_ds_swizzle((bits), ((j) << 5) | 0x10))

// DPP rotate within each 16-lane row: pure VALU cross-lane, short latency.
// ctrl: 0x121 = row_ror:1, 0x122 = row_ror:2, 0x124 = row_ror:4, 0x128 = row_ror:8
template<int CTRL>
__device__ __forceinline__ float dpp_ror(float v) {
    return __int_as_float(__builtin_amdgcn_update_dpp(
        0, __float_as_int(v), CTRL, 0xF, 0xF, true));
}

// per-edge logit+exp+accumulate, no gate (tail is peeled by the caller):
//   em via 8 ds_swizzle half2 broadcasts + 2 chains of 4 fdot2 (f32 accum,
//   seeded with xlv+xrc); leaky; att scale; 16-lane row-sum via 4 DPP
//   rotate-adds; exp; accumulate.
__device__ __forceinline__ void edge_step10(
    int eab, float xlv, float xrc, float attc,
    h2 wp0, h2 wp1, h2 wp2, h2 wp3, h2 wp4, h2 wp5, h2 wp6, h2 wp7,
    float& acc, float& l) {
    float a = FDOT2(wp3, BCH(eab, 3),
              FDOT2(wp2, BCH(eab, 2),
              FDOT2(wp1, BCH(eab, 1),
              FDOT2(wp0, BCH(eab, 0), xlv + xrc))));
    float b = FDOT2(wp7, BCH(eab, 7),
              FDOT2(wp6, BCH(eab, 6),
              FDOT2(wp5, BCH(eab, 5),
              FDOT2(wp4, BCH(eab, 4), 0.f))));
    float v = a + b;
    v = fmaxf(v, 0.f) + NEG_SLOPE * fminf(v, 0.f);
    v *= attc;
    v += dpp_ror<0x121>(v);
    v += dpp_ror<0x122>(v);
    v += dpp_ror<0x124>(v);
    v += dpp_ror<0x128>(v);
    const float pt = __expf(v);
    acc = __fmaf_rn(pt, xlv, acc);
    l  += pt;
}

// ====== fused attention v10 (sorted path): 1 node per 80-thread group =======
// 4 edges/iter, gate-free main loop + statically-indexed predicated tail
// (t is group-uniform and groups are 16-row aligned, so swizzle/DPP source
// lanes share the branch). Prefetch: src offsets 1 quad ahead of the xl
// gathers; ea/xl values 1 iteration ahead. Base pointers hoisted per lane.
// Pads (EPAD=16, zeroed) keep every prefetch in-bounds; pad-driven data is
// never accumulated.
__global__ __launch_bounds__(320) void k_fused10(
    const float* __restrict__ xl, const float* __restrict__ xr,
    const int* __restrict__ eh,    // CSR-ordered f16-pair rows (8 ints/edge)
    const float* __restrict__ we, const float* __restrict__ att,
    const int* __restrict__ src_s,
    const int* __restrict__ rowstart, const int* __restrict__ nodeord,
    const float* __restrict__ bias, float* __restrict__ out, int relu) {
    const int t = threadIdx.x;
    const int group = t / 80;
    const int c = t - group * 80;
    const int idx = blockIdx.x * 4 + group;
    if (idx >= N_NODES) return;
    const int n = nodeord[idx];
    const int pj = c & 7;

    // weights as 8 half2 pairs (f16 rounding; verified harmless in v9)
    const float4* w4 = (const float4*)(we + c * ED_DIM);
    const float4 wa = w4[0], wb = w4[1], wc = w4[2], wd = w4[3];
    const h2 wp0 = PKH2(wa.x, wa.y), wp1 = PKH2(wa.z, wa.w);
    const h2 wp2 = PKH2(wb.x, wb.y), wp3 = PKH2(wb.z, wb.w);
    const h2 wp4 = PKH2(wc.x, wc.y), wp5 = PKH2(wc.z, wc.w);
    const h2 wp6 = PKH2(wd.x, wd.y), wp7 = PKH2(wd.z, wd.w);

    const float attc = att[c];
    const float bc   = bias[c];
    const float xrc  = xr[n * HC + c];

    const int rs = rowstart[n], re = rowstart[n + 1];
    float l = 0.f, acc = 0.f;

    if (rs < re) {
        const float* xlc = xl + c;                    // per-lane base
        const int*   sp  = src_s + rs;
        const int*   ep  = eh + (size_t)rs * 8 + pj;

        // preamble: xl+ea values for quad 0 in flight; offsets for quad 1
        const int o0 = sp[0], o1 = sp[1], o2 = sp[2], o3 = sp[3];
        int n0 = sp[4], n1 = sp[5], n2 = sp[6], n3 = sp[7];
        sp += 8;
        float xA = xlc[o0], xB = xlc[o1], xC = xlc[o2], xD = xlc[o3];
        int eA = ep[0], eB = ep[8], eC = ep[16], eD = ep[24];
        ep += 32;

        const int nq = (re - rs) >> 2;
        for (int q = 0; q < nq; ++q) {
            const float x0 = xA, x1 = xB, x2 = xC, x3 = xD;
            const int   e0 = eA, e1 = eB, e2 = eC, e3 = eD;
            // issue next-quad loads; offsets were fetched last iteration
            xA = xlc[n0]; xB = xlc[n1]; xC = xlc[n2]; xD = xlc[n3];
            n0 = sp[0]; n1 = sp[1]; n2 = sp[2]; n3 = sp[3];
            sp += 4;
            eA = ep[0]; eB = ep[8]; eC = ep[16]; eD = ep[24];
            ep += 32;

            edge_step10(e0, x0, xrc, attc, wp0,wp1,wp2,wp3,wp4,wp5,wp6,wp7, acc, l);
            edge_step10(e1, x1, xrc, attc, wp0,wp1,wp2,wp3,wp4,wp5,wp6,wp7, acc, l);
            edge_step10(e2, x2, xrc, attc, wp0,wp1,wp2,wp3,wp4,wp5,wp6,wp7, acc, l);
            edge_step10(e3, x3, xrc, attc, wp0,wp1,wp2,wp3,wp4,wp5,wp6,wp7, acc, l);
        }
        // tail: 0..3 edges, values already in (xA,eA)..(xC,eC)
        const int tl = (re - rs) & 3;
        if (tl > 0) edge_step10(eA, xA, xrc, attc, wp0,wp1,wp2,wp3,wp4,wp5,wp6,wp7, acc, l);
        if (tl > 1) edge_step10(eB, xB, xrc, attc, wp0,wp1,wp2,wp3,wp4,wp5,wp6,wp7, acc, l);
        if (tl > 2) edge_step10(eC, xC, xrc, attc, wp0,wp1,wp2,wp3,wp4,wp5,wp6,wp7, acc, l);
    }
    float o = acc / (l + 1e-16f) + bc;
    if (relu) o = fmaxf(o, 0.f);
    out[n * HC + c] = o;
}

// fallback (workspace too small for eattr_h): v9-style gated 2-edge loop
__global__ __launch_bounds__(320) void k_fused_nb(
    const float* __restrict__ xl, const float* __restrict__ xr,
    const float* __restrict__ ef,
    const float* __restrict__ we, const float* __restrict__ att,
    const int* __restrict__ perm, const int* __restrict__ src_s,
    const int* __restrict__ rowstart, const int* __restrict__ nodeord,
    const float* __restrict__ bias, float* __restrict__ out, int relu) {
    const int t = threadIdx.x;
    const int group = t / 80;
    const int c = t - group * 80;
    const int idx = blockIdx.x * 4 + group;
    if (idx >= N_NODES) return;
    const int n = nodeord[idx];
    const int pj = c & 7;

    const float4* w4 = (const float4*)(we + c * ED_DIM);
    const float4 wa = w4[0], wb = w4[1], wc = w4[2], wd = w4[3];
    const h2 wp0 = PKH2(wa.x, wa.y), wp1 = PKH2(wa.z, wa.w);
    const h2 wp2 = PKH2(wb.x, wb.y), wp3 = PKH2(wb.z, wb.w);
    const h2 wp4 = PKH2(wc.x, wc.y), wp5 = PKH2(wc.z, wc.w);
    const h2 wp6 = PKH2(wd.x, wd.y), wp7 = PKH2(wd.z, wd.w);

    const float attc = att[c];
    const float bc   = bias[c];
    const float xrc  = xr[n * HC + c];

    const int rs = rowstart[n], re = rowstart[n + 1];
    float l = 0.f, acc = 0.f;

    if (rs < re) {
        const int o0 = src_s[rs];
        const int o1 = src_s[rs + 1];
        int sA = src_s[rs + 2];
        int sB = src_s[rs + 3];
        float xlA = xl[o0 + c];
        float xlB = xl[o1 + c];
        const int e0i = perm[rs], e1i = perm[rs + 1];
        const float2 f0 = *(const float2*)(ef + (size_t)e0i * ED_DIM + 2 * pj);
        const float2 f1 = *(const float2*)(ef + (size_t)e1i * ED_DIM + 2 * pj);
        int eaA = __builtin_bit_cast(int, PKH2(f0.x, f0.y));
        int eaB = __builtin_bit_cast(int, PKH2(f1.x, f1.y));

        for (int p = rs; p < re; p += 2) {
            const float xl0 = xlA, xl1 = xlB;
            const int ea0 = eaA, ea1 = eaB;
            xlA = xl[sA + c];
            xlB = xl[sB + c];
            sA = src_s[p + 4];
            sB = src_s[p + 5];
            const int en0 = perm[p + 2], en1 = perm[p + 3];
            const float2 g0 = *(const float2*)(ef + (size_t)en0 * ED_DIM + 2 * pj);
            const float2 g1 = *(const float2*)(ef + (size_t)en1 * ED_DIM + 2 * pj);
            eaA = __builtin_bit_cast(int, PKH2(g0.x, g0.y));
            eaB = __builtin_bit_cast(int, PKH2(g1.x, g1.y));

            float acc0 = 0.f, l0 = 0.f;
            edge_step10(ea0, xl0, xrc, attc, wp0,wp1,wp2,wp3,wp4,wp5,wp6,wp7, acc0, l0);
            acc += acc0; l += l0;
            if (p + 1 < re) {
                edge_step10(ea1, xl1, xrc, attc, wp0,wp1,wp2,wp3,wp4,wp5,wp6,wp7, acc, l);
            }
        }
    }
    float o = acc / (l + 1e-16f) + bc;
    if (relu) o = fmaxf(o, 0.f);
    out[n * HC + c] = o;
}

extern "C" void kernel_launch(void* const* d_in, const int* in_sizes, int n_in,
                              void* d_out, int out_size, void* d_ws, size_t ws_size,
                              hipStream_t stream) {
    (void)in_sizes; (void)n_in; (void)out_size;
    const float* x     = (const float*)d_in[0];
    const int*   ei    = (const int*)d_in[1];
    const float* eattr = (const float*)d_in[2];
    const int* srcp = ei;
    const int* dstp = ei + N_EDGES;

    // workspace layout
    float* h      = (float*)d_ws;                            // N*80
    float* xl     = h  + (size_t)N_NODES*HC;                 // N*80
    float* xr     = xl + (size_t)N_NODES*HC;                 // N*80
    int* rowstart = (int*)(xr + (size_t)N_NODES*HC);         // N+1
    int* cursor   = rowstart + (N_NODES + 1);                // N
    int* perm     = cursor + N_NODES;                        // E + EPAD
    int* src_s    = perm + N_EDGES + EPAD;                   // E + EPAD
    int* partial  = src_s + N_EDGES + EPAD;                  // SCAN_G
    int* blockoff = partial + SCAN_G;                        // SCAN_G
    int* dhist    = blockoff + SCAN_G;                       // DBIN
    int* dcur     = dhist + DBIN;                            // DBIN
    int* nodeord  = dcur + DBIN;                             // N
    // 64B-align eattr_h: rows are 32B (8 half2 words), written with int4 pairs
    int* eattr_h = (int*)(((uintptr_t)(nodeord + N_NODES) + 63) &
                          ~(uintptr_t)63);                   // (E+16)*8 ints
    float* outp   = (float*)d_out;

    const size_t need_sorted =
        (size_t)((char*)(eattr_h + (size_t)(N_EDGES + EPAD) * 8) - (char*)d_ws);
    const bool use_sorted = (ws_size >= need_sorted);

    const dim3 bx(320);
    const dim3 gx((N_NODES + 63) / 64);
    const dim3 gf((N_NODES + 3) / 4);
    const dim3 geb((N_EDGES + 255) / 256);
    const dim3 gnb((N_NODES + 255) / 256);

    // ---- build CSR by destination + degree-sorted node order (once) ----
    hipMemsetAsync(cursor, 0, (size_t)N_NODES * sizeof(int), stream);
    hipMemsetAsync(dhist, 0, DBIN * sizeof(int), stream);
    k_hist<<<geb, 256, 0, stream>>>(dstp, cursor);
    k_part<<<SCAN_G, SCAN_B, 0, stream>>>(cursor, partial);
    k_scanp<<<1, 512, 0, stream>>>(partial, blockoff, rowstart);
    k_apply<<<SCAN_G, SCAN_B, 0, stream>>>(cursor, blockoff, rowstart, dhist);
    k_degoff<<<1, 64, 0, stream>>>(dhist, dcur, perm, src_s);
    k_degplace<<<gnb, 256, 0, stream>>>(cursor, dcur, nodeord);
    hipMemsetAsync(cursor, 0, (size_t)N_NODES * sizeof(int), stream);
    if (use_sorted) {
        k_place<true><<<geb, 256, 0, stream>>>(srcp, dstp, rowstart, cursor,
                                               perm, src_s, eattr, eattr_h);
    } else {
        k_place<false><<<geb, 256, 0, stream>>>(srcp, dstp, rowstart, cursor,
                                                perm, src_s, eattr, eattr_h);
    }

    for (int L = 0; L < 3; ++L) {
        const float* in   = (L == 0) ? x : h;
        float*       oacc = (L == 2) ? outp : h;
        const float* wl   = (const float*)d_in[3 + L*7 + 0];
        const float* bl   = (const float*)d_in[3 + L*7 + 1];
        const float* wr   = (const float*)d_in[3 + L*7 + 2];
        const float* br   = (const float*)d_in[3 + L*7 + 3];
        const float* we   = (const float*)d_in[3 + L*7 + 4];
        const float* att  = (const float*)d_in[3 + L*7 + 5];
        const float* bias = (const float*)d_in[3 + L*7 + 6];

        if (L == 0) {
            k_xform2<F_IN><<<gx, bx, 0, stream>>>(in, wl, bl, wr, br, xl, xr, N_NODES);
        } else {
            k_xform2<HC><<<gx, bx, 0, stream>>>(in, wl, bl, wr, br, xl, xr, N_NODES);
        }
        if (use_sorted) {
            k_fused10<<<gf, bx, 0, stream>>>(xl, xr, eattr_h, we, att,
                                             src_s, rowstart, nodeord, bias,
                                             oacc, (L < 2) ? 1 : 0);
        } else {
            k_fused_nb<<<gf, bx, 0, stream>>>(xl, xr, eattr, we, att, perm,
                                              src_s, rowstart, nodeord, bias,
                                              oacc, (L < 2) ? 1 : 0);
        }
    }
}

// Round 8
// 849.201 us; speedup vs baseline: 1.0497x; 1.0497x over previous
//
#include <hip/hip_runtime.h>
#include <math.h>
#include <stdint.h>

#define N_NODES 100000
#define N_EDGES 1000000
#define F_IN    128
#define ED_DIM  16
#define H_HEADS 5
#define C_CH    16
#define HC      80
#define NEG_SLOPE 0.2f

#define SCAN_B 256
#define SCAN_G ((N_NODES + SCAN_B - 1) / SCAN_B)   // 391
#define DBIN 64
#define EPAD 16  // padding entries on src_s/perm; 16 zeroed pad rows on eattr_h

typedef _Float16 h2 __attribute__((ext_vector_type(2)));

#if __has_builtin(__builtin_amdgcn_fdot2)
#define FDOT2(a, b, c) __builtin_amdgcn_fdot2((a), (b), (c), false)
#else
__device__ __forceinline__ float FDOT2(h2 a, h2 b, float c) {
    return (float)a.x * (float)b.x + (float)a.y * (float)b.y + c;
}
#endif

// cvt_pkrtz returns a __fp16-vector on this clang; bit_cast to our h2
#define PKH2(x, y) __builtin_bit_cast(h2, __builtin_amdgcn_cvt_pkrtz((x), (y)))

// f16 (stored as ushort) -> f32
__device__ __forceinline__ float US2F(unsigned short u) {
    return (float)__builtin_bit_cast(_Float16, u);
}
// f32 -> f16 bits with default (RTN) rounding
__device__ __forceinline__ unsigned short F2US(float x) {
    return __builtin_bit_cast(unsigned short, (_Float16)x);
}

// ================= CSR build (graph is static across layers) =================

__global__ void k_hist(const int* __restrict__ dst, int* __restrict__ count) {
    const int e = blockIdx.x * 256 + threadIdx.x;
    if (e < N_EDGES) atomicAdd(count + dst[e], 1);
}

__global__ __launch_bounds__(SCAN_B) void k_part(const int* __restrict__ count,
                                                 int* __restrict__ partial) {
    const int i = blockIdx.x * SCAN_B + threadIdx.x;
    int v = (i < N_NODES) ? count[i] : 0;
    const int lane = threadIdx.x & 63;
    const int w    = threadIdx.x >> 6;
    __shared__ int ws[SCAN_B / 64];
    #pragma unroll
    for (int o = 32; o > 0; o >>= 1) v += __shfl_down(v, o, 64);
    if (lane == 0) ws[w] = v;
    __syncthreads();
    if (threadIdx.x == 0) {
        int s = 0;
        #pragma unroll
        for (int k = 0; k < SCAN_B / 64; ++k) s += ws[k];
        partial[blockIdx.x] = s;
    }
}

__global__ __launch_bounds__(512) void k_scanp(const int* __restrict__ partial,
                                               int* __restrict__ blockoff,
                                               int* __restrict__ rowstart) {
    __shared__ int s[512];
    const int t = threadIdx.x;
    int v = (t < SCAN_G) ? partial[t] : 0;
    s[t] = v;
    __syncthreads();
    for (int o = 1; o < 512; o <<= 1) {
        int u = (t >= o) ? s[t - o] : 0;
        __syncthreads();
        s[t] += u;
        __syncthreads();
    }
    if (t < SCAN_G) blockoff[t] = (t == 0) ? 0 : s[t - 1];
    if (t == 0) rowstart[N_NODES] = s[511];
}

// scan-apply + degree histogram fused (same node-domain pass)
__global__ __launch_bounds__(SCAN_B) void k_apply(const int* __restrict__ count,
                                                  const int* __restrict__ blockoff,
                                                  int* __restrict__ rowstart,
                                                  int* __restrict__ dhist) {
    __shared__ int s[SCAN_B];
    __shared__ int lh[DBIN];
    const int i = blockIdx.x * SCAN_B + threadIdx.x;
    const int t = threadIdx.x;
    const int v = (i < N_NODES) ? count[i] : 0;
    s[t] = v;
    if (t < DBIN) lh[t] = 0;
    __syncthreads();
    for (int o = 1; o < SCAN_B; o <<= 1) {
        int u = (t >= o) ? s[t - o] : 0;
        __syncthreads();
        s[t] += u;
        __syncthreads();
    }
    if (i < N_NODES) {
        rowstart[i] = blockoff[blockIdx.x] + (s[t] - v);
        atomicAdd(&lh[min(v, DBIN - 1)], 1);
    }
    __syncthreads();
    if (t < DBIN && lh[t] > 0) atomicAdd(dhist + t, lh[t]);
}

// place edge into CSR slot; src_s stores src*HC (pre-scaled for the hot loop);
// if COPY, also convert+copy the eattr row into CSR order as 16 f16 (32B),
// packed as 8 half2 words. Pad rows (N_EDGES..N_EDGES+EPAD) are zeroed so
// prefetch overshoot reads zeros (tail is predicated off; garbage never used).
template<bool COPY>
__global__ void k_place(const int* __restrict__ src, const int* __restrict__ dst,
                        const int* __restrict__ rowstart, int* __restrict__ cursor,
                        int* __restrict__ perm, int* __restrict__ src_s,
                        const float* __restrict__ eattr, int* __restrict__ eattr_h) {
    const int e = blockIdx.x * 256 + threadIdx.x;
    if (e >= N_EDGES) return;
    const int d = dst[e];
    const int pos = rowstart[d] + atomicAdd(cursor + d, 1);
    src_s[pos] = src[e] * HC;
    if (COPY) {
        const float4* s4 = (const float4*)(eattr + (size_t)e * ED_DIM);
        const float4 r0 = s4[0], r1 = s4[1], r2 = s4[2], r3 = s4[3];
        int4* d4 = (int4*)(eattr_h + (size_t)pos * 8);
        d4[0] = make_int4(__builtin_bit_cast(int, PKH2(r0.x, r0.y)),
                          __builtin_bit_cast(int, PKH2(r0.z, r0.w)),
                          __builtin_bit_cast(int, PKH2(r1.x, r1.y)),
                          __builtin_bit_cast(int, PKH2(r1.z, r1.w)));
        d4[1] = make_int4(__builtin_bit_cast(int, PKH2(r2.x, r2.y)),
                          __builtin_bit_cast(int, PKH2(r2.z, r2.w)),
                          __builtin_bit_cast(int, PKH2(r3.x, r3.y)),
                          __builtin_bit_cast(int, PKH2(r3.z, r3.w)));
        if (e < EPAD) {   // zero pad row N_EDGES+e (never hit by the scatter)
            int4* p4 = (int4*)(eattr_h + (size_t)(N_EDGES + e) * 8);
            p4[0] = make_int4(0, 0, 0, 0);
            p4[1] = make_int4(0, 0, 0, 0);
        }
    } else {
        perm[pos] = e;
    }
}

// also zeroes the perm/src_s padding (ws is re-poisoned before every launch)
__global__ void k_degoff(const int* __restrict__ dhist, int* __restrict__ dcur,
                         int* __restrict__ perm, int* __restrict__ src_s) {
    if (threadIdx.x == 0) {
        int off = 0;
        for (int b = DBIN - 1; b >= 0; --b) { dcur[b] = off; off += dhist[b]; }
        for (int i = 0; i < EPAD; ++i) {
            perm[N_EDGES + i]  = 0;
            src_s[N_EDGES + i] = 0;
        }
    }
}

__global__ __launch_bounds__(256) void k_degplace(const int* __restrict__ cnt,
                                                  int* __restrict__ dcur,
                                                  int* __restrict__ nodeord) {
    __shared__ int lh[DBIN];
    __shared__ int base[DBIN];
    const int t = threadIdx.x;
    if (t < DBIN) lh[t] = 0;
    __syncthreads();
    const int n = blockIdx.x * 256 + t;
    int b = 0, r = 0;
    if (n < N_NODES) {
        b = min(cnt[n], DBIN - 1);
        r = atomicAdd(&lh[b], 1);
    }
    __syncthreads();
    if (t < DBIN && lh[t] > 0) base[t] = atomicAdd(dcur + t, lh[t]);
    __syncthreads();
    if (n < N_NODES) nodeord[base[b] + r] = n;
}

// ====== fused dual node transform: xl(f16) = A@WL^T+bL, xr(f32) = A@WR^T+bR ==
// xl is written as f16 (RTN) because the fused kernel's random gather of xl
// is L2-miss-line-rate bound: halving the row (320B->160B) halves the miss
// traffic. xr / h stay f32.
template<int DIN>
__global__ __launch_bounds__(320) void k_xform2(
    const float* __restrict__ A,
    const float* __restrict__ WL, const float* __restrict__ bL,
    const float* __restrict__ WR, const float* __restrict__ bR,
    unsigned short* __restrict__ outL16, float* __restrict__ outR, int nn) {
    __shared__ float As[16][68];
    __shared__ float WsL[16][80];
    __shared__ float WsR[16][80];
    const int t  = threadIdx.x;
    const int n0 = blockIdx.x * 64;
    const int tn = (t & 15) * 4;
    const int tj = (t >> 4) * 4;
    float4 accL[4], accR[4];
    #pragma unroll
    for (int u = 0; u < 4; ++u) {
        accL[u] = make_float4(0.f, 0.f, 0.f, 0.f);
        accR[u] = make_float4(0.f, 0.f, 0.f, 0.f);
    }

    for (int k0 = 0; k0 < DIN; k0 += 16) {
        __syncthreads();
        for (int i = t; i < 64*16; i += 320) {
            int nl = i >> 4, kk = i & 15;
            int n = n0 + nl;
            As[kk][nl] = (n < nn) ? A[(size_t)n*DIN + k0 + kk] : 0.f;
        }
        for (int i = t; i < 80*16; i += 320) {
            int jj = i >> 4, kk = i & 15;
            WsL[kk][jj] = WL[(size_t)jj*DIN + k0 + kk];
            WsR[kk][jj] = WR[(size_t)jj*DIN + k0 + kk];
        }
        __syncthreads();
        #pragma unroll
        for (int k = 0; k < 16; ++k) {
            const float4 av = *(const float4*)&As[k][tn];
            const float4 wl = *(const float4*)&WsL[k][tj];
            const float4 wr = *(const float4*)&WsR[k][tj];
            accL[0].x += av.x*wl.x; accL[0].y += av.x*wl.y; accL[0].z += av.x*wl.z; accL[0].w += av.x*wl.w;
            accL[1].x += av.y*wl.x; accL[1].y += av.y*wl.y; accL[1].z += av.y*wl.z; accL[1].w += av.y*wl.w;
            accL[2].x += av.z*wl.x; accL[2].y += av.z*wl.y; accL[2].z += av.z*wl.z; accL[2].w += av.z*wl.w;
            accL[3].x += av.w*wl.x; accL[3].y += av.w*wl.y; accL[3].z += av.w*wl.z; accL[3].w += av.w*wl.w;
            accR[0].x += av.x*wr.x; accR[0].y += av.x*wr.y; accR[0].z += av.x*wr.z; accR[0].w += av.x*wr.w;
            accR[1].x += av.y*wr.x; accR[1].y += av.y*wr.y; accR[1].z += av.y*wr.z; accR[1].w += av.y*wr.w;
            accR[2].x += av.z*wr.x; accR[2].y += av.z*wr.y; accR[2].z += av.z*wr.z; accR[2].w += av.z*wr.w;
            accR[3].x += av.w*wr.x; accR[3].y += av.w*wr.y; accR[3].z += av.w*wr.z; accR[3].w += av.w*wr.w;
        }
    }
    const float4 bvL = *(const float4*)(bL + tj);
    const float4 bvR = *(const float4*)(bR + tj);
    #pragma unroll
    for (int u = 0; u < 4; ++u) {
        int n = n0 + tn + u;
        if (n < nn) {
            const float ox = accL[u].x + bvL.x, oy = accL[u].y + bvL.y;
            const float oz = accL[u].z + bvL.z, ow = accL[u].w + bvL.w;
            int2 p;
            p.x = (int)F2US(ox) | ((int)F2US(oy) << 16);
            p.y = (int)F2US(oz) | ((int)F2US(ow) << 16);
            *(int2*)(outL16 + (size_t)n*HC + tj) = p;
            float4 o;
            o.x = accR[u].x + bvR.x; o.y = accR[u].y + bvR.y;
            o.z = accR[u].z + bvR.z; o.w = accR[u].w + bvR.w;
            *(float4*)(outR + (size_t)n*HC + tj) = o;
        }
    }
}

// cross-lane helpers.
// BCH: compile-time ds_swizzle broadcast of a half2 word (DS pipe):
//   imm = (j<<5)|0x10 -> lane i reads lane (i&0x10)|j, i.e. each 16-lane row
//   gets pair j held by its own lane j. j in 0..7 covers the 16 f16 values.
#define BCH(bits, j) __builtin_bit_cast(h2, \
    __builtin_amdgcn_ds_swizzle((bits), ((j) << 5) | 0x10))

// DPP rotate within each 16-lane row: pure VALU cross-lane, short latency.
// ctrl: 0x121 = row_ror:1, 0x122 = row_ror:2, 0x124 = row_ror:4, 0x128 = row_ror:8
template<int CTRL>
__device__ __forceinline__ float dpp_ror(float v) {
    return __int_as_float(__builtin_amdgcn_update_dpp(
        0, __float_as_int(v), CTRL, 0xF, 0xF, true));
}

// per-edge logit+exp+accumulate, no gate (tail is peeled by the caller):
//   em via 8 ds_swizzle half2 broadcasts + 2 chains of 4 fdot2 (f32 accum,
//   seeded with xlv+xrc); leaky; att scale; 16-lane row-sum via 4 DPP
//   rotate-adds; exp; accumulate.
__device__ __forceinline__ void edge_step10(
    int eab, float xlv, float xrc, float attc,
    h2 wp0, h2 wp1, h2 wp2, h2 wp3, h2 wp4, h2 wp5, h2 wp6, h2 wp7,
    float& acc, float& l) {
    float a = FDOT2(wp3, BCH(eab, 3),
              FDOT2(wp2, BCH(eab, 2),
              FDOT2(wp1, BCH(eab, 1),
              FDOT2(wp0, BCH(eab, 0), xlv + xrc))));
    float b = FDOT2(wp7, BCH(eab, 7),
              FDOT2(wp6, BCH(eab, 6),
              FDOT2(wp5, BCH(eab, 5),
              FDOT2(wp4, BCH(eab, 4), 0.f))));
    float v = a + b;
    v = fmaxf(v, 0.f) + NEG_SLOPE * fminf(v, 0.f);
    v *= attc;
    v += dpp_ror<0x121>(v);
    v += dpp_ror<0x122>(v);
    v += dpp_ror<0x124>(v);
    v += dpp_ror<0x128>(v);
    const float pt = __expf(v);
    acc = __fmaf_rn(pt, xlv, acc);
    l  += pt;
}

// ====== fused attention v11 (sorted path): 1 node per 80-thread group =======
// Identical loop structure to v10, but xl is an f16 table (rows 160B):
// the random per-edge gather was L2-miss-line-rate bound at f32.
__global__ __launch_bounds__(320) void k_fused11(
    const unsigned short* __restrict__ xl16, const float* __restrict__ xr,
    const int* __restrict__ eh,    // CSR-ordered f16-pair rows (8 ints/edge)
    const float* __restrict__ we, const float* __restrict__ att,
    const int* __restrict__ src_s,
    const int* __restrict__ rowstart, const int* __restrict__ nodeord,
    const float* __restrict__ bias, float* __restrict__ out, int relu) {
    const int t = threadIdx.x;
    const int group = t / 80;
    const int c = t - group * 80;
    const int idx = blockIdx.x * 4 + group;
    if (idx >= N_NODES) return;
    const int n = nodeord[idx];
    const int pj = c & 7;

    // weights as 8 half2 pairs (f16 rounding; verified harmless in v9)
    const float4* w4 = (const float4*)(we + c * ED_DIM);
    const float4 wa = w4[0], wb = w4[1], wc = w4[2], wd = w4[3];
    const h2 wp0 = PKH2(wa.x, wa.y), wp1 = PKH2(wa.z, wa.w);
    const h2 wp2 = PKH2(wb.x, wb.y), wp3 = PKH2(wb.z, wb.w);
    const h2 wp4 = PKH2(wc.x, wc.y), wp5 = PKH2(wc.z, wc.w);
    const h2 wp6 = PKH2(wd.x, wd.y), wp7 = PKH2(wd.z, wd.w);

    const float attc = att[c];
    const float bc   = bias[c];
    const float xrc  = xr[n * HC + c];

    const int rs = rowstart[n], re = rowstart[n + 1];
    float l = 0.f, acc = 0.f;

    if (rs < re) {
        const unsigned short* xlc = xl16 + c;        // per-lane base
        const int*   sp  = src_s + rs;
        const int*   ep  = eh + (size_t)rs * 8 + pj;

        // preamble: xl+ea values for quad 0 in flight; offsets for quad 1
        const int o0 = sp[0], o1 = sp[1], o2 = sp[2], o3 = sp[3];
        int n0 = sp[4], n1 = sp[5], n2 = sp[6], n3 = sp[7];
        sp += 8;
        float xA = US2F(xlc[o0]), xB = US2F(xlc[o1]);
        float xC = US2F(xlc[o2]), xD = US2F(xlc[o3]);
        int eA = ep[0], eB = ep[8], eC = ep[16], eD = ep[24];
        ep += 32;

        const int nq = (re - rs) >> 2;
        for (int q = 0; q < nq; ++q) {
            const float x0 = xA, x1 = xB, x2 = xC, x3 = xD;
            const int   e0 = eA, e1 = eB, e2 = eC, e3 = eD;
            // issue next-quad loads; offsets were fetched last iteration
            xA = US2F(xlc[n0]); xB = US2F(xlc[n1]);
            xC = US2F(xlc[n2]); xD = US2F(xlc[n3]);
            n0 = sp[0]; n1 = sp[1]; n2 = sp[2]; n3 = sp[3];
            sp += 4;
            eA = ep[0]; eB = ep[8]; eC = ep[16]; eD = ep[24];
            ep += 32;

            edge_step10(e0, x0, xrc, attc, wp0,wp1,wp2,wp3,wp4,wp5,wp6,wp7, acc, l);
            edge_step10(e1, x1, xrc, attc, wp0,wp1,wp2,wp3,wp4,wp5,wp6,wp7, acc, l);
            edge_step10(e2, x2, xrc, attc, wp0,wp1,wp2,wp3,wp4,wp5,wp6,wp7, acc, l);
            edge_step10(e3, x3, xrc, attc, wp0,wp1,wp2,wp3,wp4,wp5,wp6,wp7, acc, l);
        }
        // tail: 0..3 edges, values already in (xA,eA)..(xC,eC)
        const int tl = (re - rs) & 3;
        if (tl > 0) edge_step10(eA, xA, xrc, attc, wp0,wp1,wp2,wp3,wp4,wp5,wp6,wp7, acc, l);
        if (tl > 1) edge_step10(eB, xB, xrc, attc, wp0,wp1,wp2,wp3,wp4,wp5,wp6,wp7, acc, l);
        if (tl > 2) edge_step10(eC, xC, xrc, attc, wp0,wp1,wp2,wp3,wp4,wp5,wp6,wp7, acc, l);
    }
    float o = acc / (l + 1e-16f) + bc;
    if (relu) o = fmaxf(o, 0.f);
    out[n * HC + c] = o;
}

// fallback (workspace too small for eattr_h): gated 2-edge loop, f16 xl
__global__ __launch_bounds__(320) void k_fused_nb(
    const unsigned short* __restrict__ xl16, const float* __restrict__ xr,
    const float* __restrict__ ef,
    const float* __restrict__ we, const float* __restrict__ att,
    const int* __restrict__ perm, const int* __restrict__ src_s,
    const int* __restrict__ rowstart, const int* __restrict__ nodeord,
    const float* __restrict__ bias, float* __restrict__ out, int relu) {
    const int t = threadIdx.x;
    const int group = t / 80;
    const int c = t - group * 80;
    const int idx = blockIdx.x * 4 + group;
    if (idx >= N_NODES) return;
    const int n = nodeord[idx];
    const int pj = c & 7;

    const float4* w4 = (const float4*)(we + c * ED_DIM);
    const float4 wa = w4[0], wb = w4[1], wc = w4[2], wd = w4[3];
    const h2 wp0 = PKH2(wa.x, wa.y), wp1 = PKH2(wa.z, wa.w);
    const h2 wp2 = PKH2(wb.x, wb.y), wp3 = PKH2(wb.z, wb.w);
    const h2 wp4 = PKH2(wc.x, wc.y), wp5 = PKH2(wc.z, wc.w);
    const h2 wp6 = PKH2(wd.x, wd.y), wp7 = PKH2(wd.z, wd.w);

    const float attc = att[c];
    const float bc   = bias[c];
    const float xrc  = xr[n * HC + c];

    const int rs = rowstart[n], re = rowstart[n + 1];
    float l = 0.f, acc = 0.f;

    if (rs < re) {
        const int o0 = src_s[rs];
        const int o1 = src_s[rs + 1];
        int sA = src_s[rs + 2];
        int sB = src_s[rs + 3];
        float xlA = US2F(xl16[o0 + c]);
        float xlB = US2F(xl16[o1 + c]);
        const int e0i = perm[rs], e1i = perm[rs + 1];
        const float2 f0 = *(const float2*)(ef + (size_t)e0i * ED_DIM + 2 * pj);
        const float2 f1 = *(const float2*)(ef + (size_t)e1i * ED_DIM + 2 * pj);
        int eaA = __builtin_bit_cast(int, PKH2(f0.x, f0.y));
        int eaB = __builtin_bit_cast(int, PKH2(f1.x, f1.y));

        for (int p = rs; p < re; p += 2) {
            const float xl0 = xlA, xl1 = xlB;
            const int ea0 = eaA, ea1 = eaB;
            xlA = US2F(xl16[sA + c]);
            xlB = US2F(xl16[sB + c]);
            sA = src_s[p + 4];
            sB = src_s[p + 5];
            const int en0 = perm[p + 2], en1 = perm[p + 3];
            const float2 g0 = *(const float2*)(ef + (size_t)en0 * ED_DIM + 2 * pj);
            const float2 g1 = *(const float2*)(ef + (size_t)en1 * ED_DIM + 2 * pj);
            eaA = __builtin_bit_cast(int, PKH2(g0.x, g0.y));
            eaB = __builtin_bit_cast(int, PKH2(g1.x, g1.y));

            float acc0 = 0.f, l0 = 0.f;
            edge_step10(ea0, xl0, xrc, attc, wp0,wp1,wp2,wp3,wp4,wp5,wp6,wp7, acc0, l0);
            acc += acc0; l += l0;
            if (p + 1 < re) {
                edge_step10(ea1, xl1, xrc, attc, wp0,wp1,wp2,wp3,wp4,wp5,wp6,wp7, acc, l);
            }
        }
    }
    float o = acc / (l + 1e-16f) + bc;
    if (relu) o = fmaxf(o, 0.f);
    out[n * HC + c] = o;
}

extern "C" void kernel_launch(void* const* d_in, const int* in_sizes, int n_in,
                              void* d_out, int out_size, void* d_ws, size_t ws_size,
                              hipStream_t stream) {
    (void)in_sizes; (void)n_in; (void)out_size;
    const float* x     = (const float*)d_in[0];
    const int*   ei    = (const int*)d_in[1];
    const float* eattr = (const float*)d_in[2];
    const int* srcp = ei;
    const int* dstp = ei + N_EDGES;

    // workspace layout
    float* h      = (float*)d_ws;                            // N*80 f32
    unsigned short* xl16 = (unsigned short*)(h + (size_t)N_NODES*HC); // N*80 f16
    float* xr     = (float*)(xl16 + (size_t)N_NODES*HC);     // N*80 f32
    int* rowstart = (int*)(xr + (size_t)N_NODES*HC);         // N+1
    int* cursor   = rowstart + (N_NODES + 1);                // N
    int* perm     = cursor + N_NODES;                        // E + EPAD
    int* src_s    = perm + N_EDGES + EPAD;                   // E + EPAD
    int* partial  = src_s + N_EDGES + EPAD;                  // SCAN_G
    int* blockoff = partial + SCAN_G;                        // SCAN_G
    int* dhist    = blockoff + SCAN_G;                       // DBIN
    int* dcur     = dhist + DBIN;                            // DBIN
    int* nodeord  = dcur + DBIN;                             // N
    // 64B-align eattr_h: rows are 32B (8 half2 words), written with int4 pairs
    int* eattr_h = (int*)(((uintptr_t)(nodeord + N_NODES) + 63) &
                          ~(uintptr_t)63);                   // (E+16)*8 ints
    float* outp   = (float*)d_out;

    const size_t need_sorted =
        (size_t)((char*)(eattr_h + (size_t)(N_EDGES + EPAD) * 8) - (char*)d_ws);
    const bool use_sorted = (ws_size >= need_sorted);

    const dim3 bx(320);
    const dim3 gx((N_NODES + 63) / 64);
    const dim3 gf((N_NODES + 3) / 4);
    const dim3 geb((N_EDGES + 255) / 256);
    const dim3 gnb((N_NODES + 255) / 256);

    // ---- build CSR by destination + degree-sorted node order (once) ----
    hipMemsetAsync(cursor, 0, (size_t)N_NODES * sizeof(int), stream);
    hipMemsetAsync(dhist, 0, DBIN * sizeof(int), stream);
    k_hist<<<geb, 256, 0, stream>>>(dstp, cursor);
    k_part<<<SCAN_G, SCAN_B, 0, stream>>>(cursor, partial);
    k_scanp<<<1, 512, 0, stream>>>(partial, blockoff, rowstart);
    k_apply<<<SCAN_G, SCAN_B, 0, stream>>>(cursor, blockoff, rowstart, dhist);
    k_degoff<<<1, 64, 0, stream>>>(dhist, dcur, perm, src_s);
    k_degplace<<<gnb, 256, 0, stream>>>(cursor, dcur, nodeord);
    hipMemsetAsync(cursor, 0, (size_t)N_NODES * sizeof(int), stream);
    if (use_sorted) {
        k_place<true><<<geb, 256, 0, stream>>>(srcp, dstp, rowstart, cursor,
                                               perm, src_s, eattr, eattr_h);
    } else {
        k_place<false><<<geb, 256, 0, stream>>>(srcp, dstp, rowstart, cursor,
                                                perm, src_s, eattr, eattr_h);
    }

    for (int L = 0; L < 3; ++L) {
        const float* in   = (L == 0) ? x : h;
        float*       oacc = (L == 2) ? outp : h;
        const float* wl   = (const float*)d_in[3 + L*7 + 0];
        const float* bl   = (const float*)d_in[3 + L*7 + 1];
        const float* wr   = (const float*)d_in[3 + L*7 + 2];
        const float* br   = (const float*)d_in[3 + L*7 + 3];
        const float* we   = (const float*)d_in[3 + L*7 + 4];
        const float* att  = (const float*)d_in[3 + L*7 + 5];
        const float* bias = (const float*)d_in[3 + L*7 + 6];

        if (L == 0) {
            k_xform2<F_IN><<<gx, bx, 0, stream>>>(in, wl, bl, wr, br, xl16, xr, N_NODES);
        } else {
            k_xform2<HC><<<gx, bx, 0, stream>>>(in, wl, bl, wr, br, xl16, xr, N_NODES);
        }
        if (use_sorted) {
            k_fused11<<<gf, bx, 0, stream>>>(xl16, xr, eattr_h, we, att,
                                             src_s, rowstart, nodeord, bias,
                                             oacc, (L < 2) ? 1 : 0);
        } else {
            k_fused_nb<<<gf, bx, 0, stream>>>(xl16, xr, eattr, we, att, perm,
                                              src_s, rowstart, nodeord, bias,
                                              oacc, (L < 2) ? 1 : 0);
        }
    }
}

// Round 9
// 751.566 us; speedup vs baseline: 1.1860x; 1.1299x over previous
//
#include <hip/hip_runtime.h>
#include <math.h>
#include <stdint.h>

#define N_NODES 100000
#define N_EDGES 1000000
#define F_IN    128
#define ED_DIM  16
#define H_HEADS 5
#define C_CH    16
#define HC      80
#define NEG_SLOPE 0.2f

#define SCAN_B 256
#define SCAN_G ((N_NODES + SCAN_B - 1) / SCAN_B)   // 391
#define DBIN 64
#define EPAD 16  // padding entries on src_s/perm; 16 zeroed pad rows on eattr_h

typedef _Float16 h2 __attribute__((ext_vector_type(2)));
typedef _Float16 h8 __attribute__((ext_vector_type(8)));   // MFMA A/B frag (4 VGPRs)
typedef float    fx4 __attribute__((ext_vector_type(4)));  // MFMA C/D frag

#if __has_builtin(__builtin_amdgcn_fdot2)
#define FDOT2(a, b, c) __builtin_amdgcn_fdot2((a), (b), (c), false)
#else
__device__ __forceinline__ float FDOT2(h2 a, h2 b, float c) {
    return (float)a.x * (float)b.x + (float)a.y * (float)b.y + c;
}
#endif

// cvt_pkrtz returns a __fp16-vector on this clang; bit_cast to our h2
#define PKH2(x, y) __builtin_bit_cast(h2, __builtin_amdgcn_cvt_pkrtz((x), (y)))

// f16 (stored as ushort) -> f32
__device__ __forceinline__ float US2F(unsigned short u) {
    return (float)__builtin_bit_cast(_Float16, u);
}
// f32 -> f16 bits with default (RTN) rounding
__device__ __forceinline__ unsigned short F2US(float x) {
    return __builtin_bit_cast(unsigned short, (_Float16)x);
}

// ================= CSR build (graph is static across layers) =================

__global__ void k_hist(const int* __restrict__ dst, int* __restrict__ count) {
    const int e = blockIdx.x * 256 + threadIdx.x;
    if (e < N_EDGES) atomicAdd(count + dst[e], 1);
}

__global__ __launch_bounds__(SCAN_B) void k_part(const int* __restrict__ count,
                                                 int* __restrict__ partial) {
    const int i = blockIdx.x * SCAN_B + threadIdx.x;
    int v = (i < N_NODES) ? count[i] : 0;
    const int lane = threadIdx.x & 63;
    const int w    = threadIdx.x >> 6;
    __shared__ int ws[SCAN_B / 64];
    #pragma unroll
    for (int o = 32; o > 0; o >>= 1) v += __shfl_down(v, o, 64);
    if (lane == 0) ws[w] = v;
    __syncthreads();
    if (threadIdx.x == 0) {
        int s = 0;
        #pragma unroll
        for (int k = 0; k < SCAN_B / 64; ++k) s += ws[k];
        partial[blockIdx.x] = s;
    }
}

__global__ __launch_bounds__(512) void k_scanp(const int* __restrict__ partial,
                                               int* __restrict__ blockoff,
                                               int* __restrict__ rowstart) {
    __shared__ int s[512];
    const int t = threadIdx.x;
    int v = (t < SCAN_G) ? partial[t] : 0;
    s[t] = v;
    __syncthreads();
    for (int o = 1; o < 512; o <<= 1) {
        int u = (t >= o) ? s[t - o] : 0;
        __syncthreads();
        s[t] += u;
        __syncthreads();
    }
    if (t < SCAN_G) blockoff[t] = (t == 0) ? 0 : s[t - 1];
    if (t == 0) rowstart[N_NODES] = s[511];
}

// scan-apply + degree histogram fused (same node-domain pass)
__global__ __launch_bounds__(SCAN_B) void k_apply(const int* __restrict__ count,
                                                  const int* __restrict__ blockoff,
                                                  int* __restrict__ rowstart,
                                                  int* __restrict__ dhist) {
    __shared__ int s[SCAN_B];
    __shared__ int lh[DBIN];
    const int i = blockIdx.x * SCAN_B + threadIdx.x;
    const int t = threadIdx.x;
    const int v = (i < N_NODES) ? count[i] : 0;
    s[t] = v;
    if (t < DBIN) lh[t] = 0;
    __syncthreads();
    for (int o = 1; o < SCAN_B; o <<= 1) {
        int u = (t >= o) ? s[t - o] : 0;
        __syncthreads();
        s[t] += u;
        __syncthreads();
    }
    if (i < N_NODES) {
        rowstart[i] = blockoff[blockIdx.x] + (s[t] - v);
        atomicAdd(&lh[min(v, DBIN - 1)], 1);
    }
    __syncthreads();
    if (t < DBIN && lh[t] > 0) atomicAdd(dhist + t, lh[t]);
}

// place edge into CSR slot; src_s stores src*HC (pre-scaled for the hot loop);
// if COPY, also convert+copy the eattr row into CSR order as 16 f16 (32B),
// packed as 8 half2 words. Pad rows (N_EDGES..N_EDGES+EPAD) are zeroed so
// prefetch overshoot reads zeros (tail is predicated off; garbage never used).
template<bool COPY>
__global__ void k_place(const int* __restrict__ src, const int* __restrict__ dst,
                        const int* __restrict__ rowstart, int* __restrict__ cursor,
                        int* __restrict__ perm, int* __restrict__ src_s,
                        const float* __restrict__ eattr, int* __restrict__ eattr_h) {
    const int e = blockIdx.x * 256 + threadIdx.x;
    if (e >= N_EDGES) return;
    const int d = dst[e];
    const int pos = rowstart[d] + atomicAdd(cursor + d, 1);
    src_s[pos] = src[e] * HC;
    if (COPY) {
        const float4* s4 = (const float4*)(eattr + (size_t)e * ED_DIM);
        const float4 r0 = s4[0], r1 = s4[1], r2 = s4[2], r3 = s4[3];
        int4* d4 = (int4*)(eattr_h + (size_t)pos * 8);
        d4[0] = make_int4(__builtin_bit_cast(int, PKH2(r0.x, r0.y)),
                          __builtin_bit_cast(int, PKH2(r0.z, r0.w)),
                          __builtin_bit_cast(int, PKH2(r1.x, r1.y)),
                          __builtin_bit_cast(int, PKH2(r1.z, r1.w)));
        d4[1] = make_int4(__builtin_bit_cast(int, PKH2(r2.x, r2.y)),
                          __builtin_bit_cast(int, PKH2(r2.z, r2.w)),
                          __builtin_bit_cast(int, PKH2(r3.x, r3.y)),
                          __builtin_bit_cast(int, PKH2(r3.z, r3.w)));
        if (e < EPAD) {   // zero pad row N_EDGES+e (never hit by the scatter)
            int4* p4 = (int4*)(eattr_h + (size_t)(N_EDGES + e) * 8);
            p4[0] = make_int4(0, 0, 0, 0);
            p4[1] = make_int4(0, 0, 0, 0);
        }
    } else {
        perm[pos] = e;
    }
}

// also zeroes the perm/src_s padding (ws is re-poisoned before every launch)
__global__ void k_degoff(const int* __restrict__ dhist, int* __restrict__ dcur,
                         int* __restrict__ perm, int* __restrict__ src_s) {
    if (threadIdx.x == 0) {
        int off = 0;
        for (int b = DBIN - 1; b >= 0; --b) { dcur[b] = off; off += dhist[b]; }
        for (int i = 0; i < EPAD; ++i) {
            perm[N_EDGES + i]  = 0;
            src_s[N_EDGES + i] = 0;
        }
    }
}

__global__ __launch_bounds__(256) void k_degplace(const int* __restrict__ cnt,
                                                  int* __restrict__ dcur,
                                                  int* __restrict__ nodeord) {
    __shared__ int lh[DBIN];
    __shared__ int base[DBIN];
    const int t = threadIdx.x;
    if (t < DBIN) lh[t] = 0;
    __syncthreads();
    const int n = blockIdx.x * 256 + t;
    int b = 0, r = 0;
    if (n < N_NODES) {
        b = min(cnt[n], DBIN - 1);
        r = atomicAdd(&lh[b], 1);
    }
    __syncthreads();
    if (t < DBIN && lh[t] > 0) base[t] = atomicAdd(dcur + t, lh[t]);
    __syncthreads();
    if (n < N_NODES) nodeord[base[b] + r] = n;
}

// ====== MFMA dual node transform: xl(f16) = A@WL^T+bL, xr(f32) = A@WR^T+bR ===
// One wave = 16-node x 16-out tile via v_mfma_f32_16x16x32_f16, looping the
// 80 outputs (5 tiles) with shared A-frags. No LDS, no barriers.
// Layout: A-frag lane l = A[n0+(l&15)][k0+(l>>4)*8+s]; W-frag (B operand)
// lane l = W[j0+(l&15)][same k]. A/B share the identical lane/slot->k
// structure on CDNA, so any bijective k-permutation cancels in the
// contraction — this is robust to the exact HW k-wiring. C/D layout is
// HW-verified: col=lane&15, row=(lane>>4)*4+reg.
template<int DIN>
__device__ __forceinline__ h8 ldfrag(const float* __restrict__ rowbase,
                                     int t, int kg) {
    const int kb = t * 32 + kg * 8;
    h8 v;
    if (kb + 8 <= DIN) {
        const float4 p = *(const float4*)(rowbase + t * 32);
        const float4 q = *(const float4*)(rowbase + t * 32 + 4);
        v[0] = (_Float16)p.x; v[1] = (_Float16)p.y;
        v[2] = (_Float16)p.z; v[3] = (_Float16)p.w;
        v[4] = (_Float16)q.x; v[5] = (_Float16)q.y;
        v[6] = (_Float16)q.z; v[7] = (_Float16)q.w;
    } else {
        #pragma unroll
        for (int s = 0; s < 8; ++s)
            v[s] = (_Float16)((kb + s < DIN) ? rowbase[t * 32 + s] : 0.f);
    }
    return v;
}

template<int DIN>
__global__ __launch_bounds__(256) void k_xform2m(
    const float* __restrict__ A,
    const float* __restrict__ WL, const float* __restrict__ bL,
    const float* __restrict__ WR, const float* __restrict__ bR,
    unsigned short* __restrict__ outL16, float* __restrict__ outR) {
    constexpr int KT = (DIN + 31) / 32;       // 4 for DIN=128, 3 for DIN=80
    const int l   = threadIdx.x & 63;
    const int wv  = threadIdx.x >> 6;         // wave in block (0..3)
    const int n0  = (blockIdx.x * 4 + wv) * 16;
    if (n0 >= N_NODES) return;
    const int col = l & 15;
    const int kg  = l >> 4;

    // A fragments for the whole K, reused across all 5 output tiles
    h8 af[KT];
    const float* arow = A + (size_t)(n0 + col) * DIN + kg * 8;
    #pragma unroll
    for (int t = 0; t < KT; ++t) af[t] = ldfrag<DIN>(arow, t, kg);

    #pragma unroll
    for (int j0 = 0; j0 < HC; j0 += 16) {
        fx4 cl = {0.f, 0.f, 0.f, 0.f};
        fx4 cr = {0.f, 0.f, 0.f, 0.f};
        const float* wlr = WL + (size_t)(j0 + col) * DIN + kg * 8;
        const float* wrr = WR + (size_t)(j0 + col) * DIN + kg * 8;
        #pragma unroll
        for (int t = 0; t < KT; ++t) {
            const h8 bl_ = ldfrag<DIN>(wlr, t, kg);
            const h8 br_ = ldfrag<DIN>(wrr, t, kg);
            cl = __builtin_amdgcn_mfma_f32_16x16x32_f16(af[t], bl_, cl, 0, 0, 0);
            cr = __builtin_amdgcn_mfma_f32_16x16x32_f16(af[t], br_, cr, 0, 0, 0);
        }
        const float blv = bL[j0 + col];
        const float brv = bR[j0 + col];
        #pragma unroll
        for (int i = 0; i < 4; ++i) {
            const int nn = n0 + kg * 4 + i;
            outL16[(size_t)nn * HC + j0 + col] = F2US(cl[i] + blv);
            outR [(size_t)nn * HC + j0 + col] = cr[i] + brv;
        }
    }
}

// cross-lane helpers.
// BCH: compile-time ds_swizzle broadcast of a half2 word (DS pipe):
//   imm = (j<<5)|0x10 -> lane i reads lane (i&0x10)|j, i.e. each 16-lane row
//   gets pair j held by its own lane j. j in 0..7 covers the 16 f16 values.
#define BCH(bits, j) __builtin_bit_cast(h2, \
    __builtin_amdgcn_ds_swizzle((bits), ((j) << 5) | 0x10))

// DPP rotate within each 16-lane row: pure VALU cross-lane, short latency.
// ctrl: 0x121 = row_ror:1, 0x122 = row_ror:2, 0x124 = row_ror:4, 0x128 = row_ror:8
template<int CTRL>
__device__ __forceinline__ float dpp_ror(float v) {
    return __int_as_float(__builtin_amdgcn_update_dpp(
        0, __float_as_int(v), CTRL, 0xF, 0xF, true));
}

// per-edge logit+exp+accumulate, no gate (tail is peeled by the caller):
//   em via 8 ds_swizzle half2 broadcasts + 2 chains of 4 fdot2 (f32 accum,
//   seeded with xlv+xrc); leaky; att scale; 16-lane row-sum via 4 DPP
//   rotate-adds; exp; accumulate.
__device__ __forceinline__ void edge_step10(
    int eab, float xlv, float xrc, float attc,
    h2 wp0, h2 wp1, h2 wp2, h2 wp3, h2 wp4, h2 wp5, h2 wp6, h2 wp7,
    float& acc, float& l) {
    float a = FDOT2(wp3, BCH(eab, 3),
              FDOT2(wp2, BCH(eab, 2),
              FDOT2(wp1, BCH(eab, 1),
              FDOT2(wp0, BCH(eab, 0), xlv + xrc))));
    float b = FDOT2(wp7, BCH(eab, 7),
              FDOT2(wp6, BCH(eab, 6),
              FDOT2(wp5, BCH(eab, 5),
              FDOT2(wp4, BCH(eab, 4), 0.f))));
    float v = a + b;
    v = fmaxf(v, 0.f) + NEG_SLOPE * fminf(v, 0.f);
    v *= attc;
    v += dpp_ror<0x121>(v);
    v += dpp_ror<0x122>(v);
    v += dpp_ror<0x124>(v);
    v += dpp_ror<0x128>(v);
    const float pt = __expf(v);
    acc = __fmaf_rn(pt, xlv, acc);
    l  += pt;
}

// ====== fused attention v11 (sorted path): 1 node per 80-thread group =======
// 4 edges/iter, gate-free main loop + statically-indexed predicated tail.
// xl is an f16 table (rows 160B): the random per-edge gather is
// L2-miss-line-rate bound, so smaller rows = fewer miss bytes.
__global__ __launch_bounds__(320) void k_fused11(
    const unsigned short* __restrict__ xl16, const float* __restrict__ xr,
    const int* __restrict__ eh,    // CSR-ordered f16-pair rows (8 ints/edge)
    const float* __restrict__ we, const float* __restrict__ att,
    const int* __restrict__ src_s,
    const int* __restrict__ rowstart, const int* __restrict__ nodeord,
    const float* __restrict__ bias, float* __restrict__ out, int relu) {
    const int t = threadIdx.x;
    const int group = t / 80;
    const int c = t - group * 80;
    const int idx = blockIdx.x * 4 + group;
    if (idx >= N_NODES) return;
    const int n = nodeord[idx];
    const int pj = c & 7;

    // weights as 8 half2 pairs (f16 rounding; verified harmless in v9)
    const float4* w4 = (const float4*)(we + c * ED_DIM);
    const float4 wa = w4[0], wb = w4[1], wc = w4[2], wd = w4[3];
    const h2 wp0 = PKH2(wa.x, wa.y), wp1 = PKH2(wa.z, wa.w);
    const h2 wp2 = PKH2(wb.x, wb.y), wp3 = PKH2(wb.z, wb.w);
    const h2 wp4 = PKH2(wc.x, wc.y), wp5 = PKH2(wc.z, wc.w);
    const h2 wp6 = PKH2(wd.x, wd.y), wp7 = PKH2(wd.z, wd.w);

    const float attc = att[c];
    const float bc   = bias[c];
    const float xrc  = xr[n * HC + c];

    const int rs = rowstart[n], re = rowstart[n + 1];
    float l = 0.f, acc = 0.f;

    if (rs < re) {
        const unsigned short* xlc = xl16 + c;        // per-lane base
        const int*   sp  = src_s + rs;
        const int*   ep  = eh + (size_t)rs * 8 + pj;

        // preamble: xl+ea values for quad 0 in flight; offsets for quad 1
        const int o0 = sp[0], o1 = sp[1], o2 = sp[2], o3 = sp[3];
        int n0 = sp[4], n1 = sp[5], n2 = sp[6], n3 = sp[7];
        sp += 8;
        float xA = US2F(xlc[o0]), xB = US2F(xlc[o1]);
        float xC = US2F(xlc[o2]), xD = US2F(xlc[o3]);
        int eA = ep[0], eB = ep[8], eC = ep[16], eD = ep[24];
        ep += 32;

        const int nq = (re - rs) >> 2;
        for (int q = 0; q < nq; ++q) {
            const float x0 = xA, x1 = xB, x2 = xC, x3 = xD;
            const int   e0 = eA, e1 = eB, e2 = eC, e3 = eD;
            // issue next-quad loads; offsets were fetched last iteration
            xA = US2F(xlc[n0]); xB = US2F(xlc[n1]);
            xC = US2F(xlc[n2]); xD = US2F(xlc[n3]);
            n0 = sp[0]; n1 = sp[1]; n2 = sp[2]; n3 = sp[3];
            sp += 4;
            eA = ep[0]; eB = ep[8]; eC = ep[16]; eD = ep[24];
            ep += 32;

            edge_step10(e0, x0, xrc, attc, wp0,wp1,wp2,wp3,wp4,wp5,wp6,wp7, acc, l);
            edge_step10(e1, x1, xrc, attc, wp0,wp1,wp2,wp3,wp4,wp5,wp6,wp7, acc, l);
            edge_step10(e2, x2, xrc, attc, wp0,wp1,wp2,wp3,wp4,wp5,wp6,wp7, acc, l);
            edge_step10(e3, x3, xrc, attc, wp0,wp1,wp2,wp3,wp4,wp5,wp6,wp7, acc, l);
        }
        // tail: 0..3 edges, values already in (xA,eA)..(xC,eC)
        const int tl = (re - rs) & 3;
        if (tl > 0) edge_step10(eA, xA, xrc, attc, wp0,wp1,wp2,wp3,wp4,wp5,wp6,wp7, acc, l);
        if (tl > 1) edge_step10(eB, xB, xrc, attc, wp0,wp1,wp2,wp3,wp4,wp5,wp6,wp7, acc, l);
        if (tl > 2) edge_step10(eC, xC, xrc, attc, wp0,wp1,wp2,wp3,wp4,wp5,wp6,wp7, acc, l);
    }
    float o = acc / (l + 1e-16f) + bc;
    if (relu) o = fmaxf(o, 0.f);
    out[n * HC + c] = o;
}

// fallback (workspace too small for eattr_h): gated 2-edge loop, f16 xl
__global__ __launch_bounds__(320) void k_fused_nb(
    const unsigned short* __restrict__ xl16, const float* __restrict__ xr,
    const float* __restrict__ ef,
    const float* __restrict__ we, const float* __restrict__ att,
    const int* __restrict__ perm, const int* __restrict__ src_s,
    const int* __restrict__ rowstart, const int* __restrict__ nodeord,
    const float* __restrict__ bias, float* __restrict__ out, int relu) {
    const int t = threadIdx.x;
    const int group = t / 80;
    const int c = t - group * 80;
    const int idx = blockIdx.x * 4 + group;
    if (idx >= N_NODES) return;
    const int n = nodeord[idx];
    const int pj = c & 7;

    const float4* w4 = (const float4*)(we + c * ED_DIM);
    const float4 wa = w4[0], wb = w4[1], wc = w4[2], wd = w4[3];
    const h2 wp0 = PKH2(wa.x, wa.y), wp1 = PKH2(wa.z, wa.w);
    const h2 wp2 = PKH2(wb.x, wb.y), wp3 = PKH2(wb.z, wb.w);
    const h2 wp4 = PKH2(wc.x, wc.y), wp5 = PKH2(wc.z, wc.w);
    const h2 wp6 = PKH2(wd.x, wd.y), wp7 = PKH2(wd.z, wd.w);

    const float attc = att[c];
    const float bc   = bias[c];
    const float xrc  = xr[n * HC + c];

    const int rs = rowstart[n], re = rowstart[n + 1];
    float l = 0.f, acc = 0.f;

    if (rs < re) {
        const int o0 = src_s[rs];
        const int o1 = src_s[rs + 1];
        int sA = src_s[rs + 2];
        int sB = src_s[rs + 3];
        float xlA = US2F(xl16[o0 + c]);
        float xlB = US2F(xl16[o1 + c]);
        const int e0i = perm[rs], e1i = perm[rs + 1];
        const float2 f0 = *(const float2*)(ef + (size_t)e0i * ED_DIM + 2 * pj);
        const float2 f1 = *(const float2*)(ef + (size_t)e1i * ED_DIM + 2 * pj);
        int eaA = __builtin_bit_cast(int, PKH2(f0.x, f0.y));
        int eaB = __builtin_bit_cast(int, PKH2(f1.x, f1.y));

        for (int p = rs; p < re; p += 2) {
            const float xl0 = xlA, xl1 = xlB;
            const int ea0 = eaA, ea1 = eaB;
            xlA = US2F(xl16[sA + c]);
            xlB = US2F(xl16[sB + c]);
            sA = src_s[p + 4];
            sB = src_s[p + 5];
            const int en0 = perm[p + 2], en1 = perm[p + 3];
            const float2 g0 = *(const float2*)(ef + (size_t)en0 * ED_DIM + 2 * pj);
            const float2 g1 = *(const float2*)(ef + (size_t)en1 * ED_DIM + 2 * pj);
            eaA = __builtin_bit_cast(int, PKH2(g0.x, g0.y));
            eaB = __builtin_bit_cast(int, PKH2(g1.x, g1.y));

            float acc0 = 0.f, l0 = 0.f;
            edge_step10(ea0, xl0, xrc, attc, wp0,wp1,wp2,wp3,wp4,wp5,wp6,wp7, acc0, l0);
            acc += acc0; l += l0;
            if (p + 1 < re) {
                edge_step10(ea1, xl1, xrc, attc, wp0,wp1,wp2,wp3,wp4,wp5,wp6,wp7, acc, l);
            }
        }
    }
    float o = acc / (l + 1e-16f) + bc;
    if (relu) o = fmaxf(o, 0.f);
    out[n * HC + c] = o;
}

extern "C" void kernel_launch(void* const* d_in, const int* in_sizes, int n_in,
                              void* d_out, int out_size, void* d_ws, size_t ws_size,
                              hipStream_t stream) {
    (void)in_sizes; (void)n_in; (void)out_size;
    const float* x     = (const float*)d_in[0];
    const int*   ei    = (const int*)d_in[1];
    const float* eattr = (const float*)d_in[2];
    const int* srcp = ei;
    const int* dstp = ei + N_EDGES;

    // workspace layout
    float* h      = (float*)d_ws;                            // N*80 f32
    unsigned short* xl16 = (unsigned short*)(h + (size_t)N_NODES*HC); // N*80 f16
    float* xr     = (float*)(xl16 + (size_t)N_NODES*HC);     // N*80 f32
    int* rowstart = (int*)(xr + (size_t)N_NODES*HC);         // N+1
    int* cursor   = rowstart + (N_NODES + 1);                // N
    int* perm     = cursor + N_NODES;                        // E + EPAD
    int* src_s    = perm + N_EDGES + EPAD;                   // E + EPAD
    int* partial  = src_s + N_EDGES + EPAD;                  // SCAN_G
    int* blockoff = partial + SCAN_G;                        // SCAN_G
    int* dhist    = blockoff + SCAN_G;                       // DBIN
    int* dcur     = dhist + DBIN;                            // DBIN
    int* nodeord  = dcur + DBIN;                             // N
    // 64B-align eattr_h: rows are 32B (8 half2 words), written with int4 pairs
    int* eattr_h = (int*)(((uintptr_t)(nodeord + N_NODES) + 63) &
                          ~(uintptr_t)63);                   // (E+16)*8 ints
    float* outp   = (float*)d_out;

    const size_t need_sorted =
        (size_t)((char*)(eattr_h + (size_t)(N_EDGES + EPAD) * 8) - (char*)d_ws);
    const bool use_sorted = (ws_size >= need_sorted);

    const dim3 gf((N_NODES + 3) / 4);
    const dim3 gx2((N_NODES + 63) / 64);
    const dim3 geb((N_EDGES + 255) / 256);
    const dim3 gnb((N_NODES + 255) / 256);

    // ---- build CSR by destination + degree-sorted node order (once) ----
    hipMemsetAsync(cursor, 0, (size_t)N_NODES * sizeof(int), stream);
    hipMemsetAsync(dhist, 0, DBIN * sizeof(int), stream);
    k_hist<<<geb, 256, 0, stream>>>(dstp, cursor);
    k_part<<<SCAN_G, SCAN_B, 0, stream>>>(cursor, partial);
    k_scanp<<<1, 512, 0, stream>>>(partial, blockoff, rowstart);
    k_apply<<<SCAN_G, SCAN_B, 0, stream>>>(cursor, blockoff, rowstart, dhist);
    k_degoff<<<1, 64, 0, stream>>>(dhist, dcur, perm, src_s);
    k_degplace<<<gnb, 256, 0, stream>>>(cursor, dcur, nodeord);
    hipMemsetAsync(cursor, 0, (size_t)N_NODES * sizeof(int), stream);
    if (use_sorted) {
        k_place<true><<<geb, 256, 0, stream>>>(srcp, dstp, rowstart, cursor,
                                               perm, src_s, eattr, eattr_h);
    } else {
        k_place<false><<<geb, 256, 0, stream>>>(srcp, dstp, rowstart, cursor,
                                                perm, src_s, eattr, eattr_h);
    }

    for (int L = 0; L < 3; ++L) {
        const float* in   = (L == 0) ? x : h;
        float*       oacc = (L == 2) ? outp : h;
        const float* wl   = (const float*)d_in[3 + L*7 + 0];
        const float* bl   = (const float*)d_in[3 + L*7 + 1];
        const float* wr   = (const float*)d_in[3 + L*7 + 2];
        const float* br   = (const float*)d_in[3 + L*7 + 3];
        const float* we   = (const float*)d_in[3 + L*7 + 4];
        const float* att  = (const float*)d_in[3 + L*7 + 5];
        const float* bias = (const float*)d_in[3 + L*7 + 6];

        if (L == 0) {
            k_xform2m<F_IN><<<gx2, 256, 0, stream>>>(in, wl, bl, wr, br, xl16, xr);
        } else {
            k_xform2m<HC><<<gx2, 256, 0, stream>>>(in, wl, bl, wr, br, xl16, xr);
        }
        if (use_sorted) {
            k_fused11<<<gf, 320, 0, stream>>>(xl16, xr, eattr_h, we, att,
                                              src_s, rowstart, nodeord, bias,
                                              oacc, (L < 2) ? 1 : 0);
        } else {
            k_fused_nb<<<gf, 320, 0, stream>>>(xl16, xr, eattr, we, att, perm,
                                               src_s, rowstart, nodeord, bias,
                                               oacc, (L < 2) ? 1 : 0);
        }
    }
}

// Round 10
// 677.067 us; speedup vs baseline: 1.3165x; 1.1100x over previous
//
#include <hip/hip_runtime.h>
#include <math.h>
#include <stdint.h>

#define N_NODES 100000
#define N_EDGES 1000000
#define F_IN    128
#define ED_DIM  16
#define H_HEADS 5
#define C_CH    16
#define HC      80
#define NEG_SLOPE 0.2f

#define SCAN_B 256
#define SCAN_G ((N_NODES + SCAN_B - 1) / SCAN_B)   // 391
#define DBIN 64
#define EPAD 16  // padding entries on src_s/perm; 16 zeroed pad rows on eattr_h

typedef _Float16 h2 __attribute__((ext_vector_type(2)));
typedef _Float16 h8 __attribute__((ext_vector_type(8)));   // MFMA A/B frag (4 VGPRs)
typedef float    fx4 __attribute__((ext_vector_type(4)));  // MFMA C/D frag

#if __has_builtin(__builtin_amdgcn_fdot2)
#define FDOT2(a, b, c) __builtin_amdgcn_fdot2((a), (b), (c), false)
#else
__device__ __forceinline__ float FDOT2(h2 a, h2 b, float c) {
    return (float)a.x * (float)b.x + (float)a.y * (float)b.y + c;
}
#endif

// cvt_pkrtz returns a __fp16-vector on this clang; bit_cast to our h2
#define PKH2(x, y) __builtin_bit_cast(h2, __builtin_amdgcn_cvt_pkrtz((x), (y)))

// f16 (stored as ushort) -> f32
__device__ __forceinline__ float US2F(unsigned short u) {
    return (float)__builtin_bit_cast(_Float16, u);
}
// f32 -> f16 bits with default (RTN) rounding
__device__ __forceinline__ unsigned short F2US(float x) {
    return __builtin_bit_cast(unsigned short, (_Float16)x);
}

// ================= CSR build (graph is static across layers) =================

// also zeroes dhist (block 0) so the dhist memset dispatch is dropped
__global__ void k_hist(const int* __restrict__ dst, int* __restrict__ count,
                       int* __restrict__ dhist) {
    if (blockIdx.x == 0 && threadIdx.x < DBIN) dhist[threadIdx.x] = 0;
    const int e = blockIdx.x * 256 + threadIdx.x;
    if (e < N_EDGES) atomicAdd(count + dst[e], 1);
}

__global__ __launch_bounds__(SCAN_B) void k_part(const int* __restrict__ count,
                                                 int* __restrict__ partial) {
    const int i = blockIdx.x * SCAN_B + threadIdx.x;
    int v = (i < N_NODES) ? count[i] : 0;
    const int lane = threadIdx.x & 63;
    const int w    = threadIdx.x >> 6;
    __shared__ int ws[SCAN_B / 64];
    #pragma unroll
    for (int o = 32; o > 0; o >>= 1) v += __shfl_down(v, o, 64);
    if (lane == 0) ws[w] = v;
    __syncthreads();
    if (threadIdx.x == 0) {
        int s = 0;
        #pragma unroll
        for (int k = 0; k < SCAN_B / 64; ++k) s += ws[k];
        partial[blockIdx.x] = s;
    }
}

__global__ __launch_bounds__(512) void k_scanp(const int* __restrict__ partial,
                                               int* __restrict__ blockoff,
                                               int* __restrict__ rowstart) {
    __shared__ int s[512];
    const int t = threadIdx.x;
    int v = (t < SCAN_G) ? partial[t] : 0;
    s[t] = v;
    __syncthreads();
    for (int o = 1; o < 512; o <<= 1) {
        int u = (t >= o) ? s[t - o] : 0;
        __syncthreads();
        s[t] += u;
        __syncthreads();
    }
    if (t < SCAN_G) blockoff[t] = (t == 0) ? 0 : s[t - 1];
    if (t == 0) rowstart[N_NODES] = s[511];
}

// scan-apply + degree histogram fused; also zeroes count (=cursor) after
// reading so the second cursor memset dispatch is dropped. k_degplace derives
// degrees from rowstart diffs, so zeroing here is safe.
__global__ __launch_bounds__(SCAN_B) void k_apply(int* __restrict__ count,
                                                  const int* __restrict__ blockoff,
                                                  int* __restrict__ rowstart,
                                                  int* __restrict__ dhist) {
    __shared__ int s[SCAN_B];
    __shared__ int lh[DBIN];
    const int i = blockIdx.x * SCAN_B + threadIdx.x;
    const int t = threadIdx.x;
    const int v = (i < N_NODES) ? count[i] : 0;
    s[t] = v;
    if (t < DBIN) lh[t] = 0;
    __syncthreads();
    for (int o = 1; o < SCAN_B; o <<= 1) {
        int u = (t >= o) ? s[t - o] : 0;
        __syncthreads();
        s[t] += u;
        __syncthreads();
    }
    if (i < N_NODES) {
        rowstart[i] = blockoff[blockIdx.x] + (s[t] - v);
        count[i] = 0;
        atomicAdd(&lh[min(v, DBIN - 1)], 1);
    }
    __syncthreads();
    if (t < DBIN && lh[t] > 0) atomicAdd(dhist + t, lh[t]);
}

// place edge into CSR slot; src_s stores src*HC (pre-scaled for the hot loop);
// if COPY, also convert+copy the eattr row into CSR order as 16 f16 (32B),
// packed as 8 half2 words. Pad rows (N_EDGES..N_EDGES+EPAD) are zeroed so
// prefetch overshoot reads zeros (tail is predicated off; garbage never used).
template<bool COPY>
__global__ void k_place(const int* __restrict__ src, const int* __restrict__ dst,
                        const int* __restrict__ rowstart, int* __restrict__ cursor,
                        int* __restrict__ perm, int* __restrict__ src_s,
                        const float* __restrict__ eattr, int* __restrict__ eattr_h) {
    const int e = blockIdx.x * 256 + threadIdx.x;
    if (e >= N_EDGES) return;
    const int d = dst[e];
    const int pos = rowstart[d] + atomicAdd(cursor + d, 1);
    src_s[pos] = src[e] * HC;
    if (COPY) {
        const float4* s4 = (const float4*)(eattr + (size_t)e * ED_DIM);
        const float4 r0 = s4[0], r1 = s4[1], r2 = s4[2], r3 = s4[3];
        int4* d4 = (int4*)(eattr_h + (size_t)pos * 8);
        d4[0] = make_int4(__builtin_bit_cast(int, PKH2(r0.x, r0.y)),
                          __builtin_bit_cast(int, PKH2(r0.z, r0.w)),
                          __builtin_bit_cast(int, PKH2(r1.x, r1.y)),
                          __builtin_bit_cast(int, PKH2(r1.z, r1.w)));
        d4[1] = make_int4(__builtin_bit_cast(int, PKH2(r2.x, r2.y)),
                          __builtin_bit_cast(int, PKH2(r2.z, r2.w)),
                          __builtin_bit_cast(int, PKH2(r3.x, r3.y)),
                          __builtin_bit_cast(int, PKH2(r3.z, r3.w)));
        if (e < EPAD) {   // zero pad row N_EDGES+e (never hit by the scatter)
            int4* p4 = (int4*)(eattr_h + (size_t)(N_EDGES + e) * 8);
            p4[0] = make_int4(0, 0, 0, 0);
            p4[1] = make_int4(0, 0, 0, 0);
        }
    } else {
        perm[pos] = e;
    }
}

// also zeroes the perm/src_s padding (ws is re-poisoned before every launch)
__global__ void k_degoff(const int* __restrict__ dhist, int* __restrict__ dcur,
                         int* __restrict__ perm, int* __restrict__ src_s) {
    if (threadIdx.x == 0) {
        int off = 0;
        for (int b = DBIN - 1; b >= 0; --b) { dcur[b] = off; off += dhist[b]; }
        for (int i = 0; i < EPAD; ++i) {
            perm[N_EDGES + i]  = 0;
            src_s[N_EDGES + i] = 0;
        }
    }
}

// degree from rowstart diffs (cursor was zeroed by k_apply)
__global__ __launch_bounds__(256) void k_degplace(const int* __restrict__ rowstart,
                                                  int* __restrict__ dcur,
                                                  int* __restrict__ nodeord) {
    __shared__ int lh[DBIN];
    __shared__ int base[DBIN];
    const int t = threadIdx.x;
    if (t < DBIN) lh[t] = 0;
    __syncthreads();
    const int n = blockIdx.x * 256 + t;
    int b = 0, r = 0;
    if (n < N_NODES) {
        b = min(rowstart[n + 1] - rowstart[n], DBIN - 1);
        r = atomicAdd(&lh[b], 1);
    }
    __syncthreads();
    if (t < DBIN && lh[t] > 0) base[t] = atomicAdd(dcur + t, lh[t]);
    __syncthreads();
    if (n < N_NODES) nodeord[base[b] + r] = n;
}

// ====== W fragment pre-pack (once): f32 W -> f16 MFMA fragments ==============
// Fragment = 64 lanes x 8 halfs (1KB), lane mapping IDENTICAL to the
// HW-verified round-9 ldfrag: col=l&15, k = t*32 + (l>>4)*8 + s; zeros past
// DIN. fid layout: L0 (DIN=128,KT=4): fid = m*20 + j*4 + t (0..39);
// L1 (DIN=80,KT=3): 40 + m*15 + j*3 + t; L2: 70 + m*15 + j*3 + t.
__global__ __launch_bounds__(64) void k_wpack(
    const float* __restrict__ w1l, const float* __restrict__ w1r,
    const float* __restrict__ w2l, const float* __restrict__ w2r,
    const float* __restrict__ w3l, const float* __restrict__ w3r,
    _Float16* __restrict__ wbuf) {
    const int fid = blockIdx.x;
    const int l = threadIdx.x;
    int m, j, t, DIN;
    const float* W;
    if (fid < 40)      { int r = fid;      m = r / 20; r %= 20; j = r / 4; t = r % 4;
                         DIN = 128; W = m ? w1r : w1l; }
    else if (fid < 70) { int r = fid - 40; m = r / 15; r %= 15; j = r / 3; t = r % 3;
                         DIN = 80;  W = m ? w2r : w2l; }
    else               { int r = fid - 70; m = r / 15; r %= 15; j = r / 3; t = r % 3;
                         DIN = 80;  W = m ? w3r : w3l; }
    const int col = l & 15, kg = l >> 4;
    _Float16* dst = wbuf + (size_t)fid * 512 + l * 8;
    #pragma unroll
    for (int s = 0; s < 8; ++s) {
        const int kk = t * 32 + kg * 8 + s;
        dst[s] = (_Float16)((kk < DIN) ? W[(size_t)(j * 16 + col) * DIN + kk] : 0.f);
    }
}

// ====== MFMA dual node transform v2: pre-packed W fragments ==================
// One wave = 16-node x 16-out tile; inner loop per (j,t) is 2 fragment loads
// (coalesced 16B/lane, no cvt, no branch) + 2 MFMA. j-loop kept rolled
// (#pragma unroll 1) to cap register pressure. A-frags: vector load or
// all-zero (boundary frags are entirely out of range for DIN in {128,80} —
// no scalar path, no OOB reads).
template<int DIN>
__global__ __launch_bounds__(256) void k_xform2f(
    const float* __restrict__ A,
    const _Float16* __restrict__ wfL, const _Float16* __restrict__ wfR,
    const float* __restrict__ bL, const float* __restrict__ bR,
    unsigned short* __restrict__ outL16, float* __restrict__ outR) {
    constexpr int KT = (DIN + 31) / 32;       // 4 for 128, 3 for 80
    const int l   = threadIdx.x & 63;
    const int wv  = threadIdx.x >> 6;
    const int n0  = (blockIdx.x * 4 + wv) * 16;
    if (n0 >= N_NODES) return;
    const int col = l & 15;
    const int kg  = l >> 4;

    h8 af[KT];
    const float* arow = A + (size_t)(n0 + col) * DIN + kg * 8;
    #pragma unroll
    for (int t = 0; t < KT; ++t) {
        if (t * 32 + kg * 8 + 8 <= DIN) {
            const float4 p = *(const float4*)(arow + t * 32);
            const float4 q = *(const float4*)(arow + t * 32 + 4);
            h8 v;
            v[0] = (_Float16)p.x; v[1] = (_Float16)p.y;
            v[2] = (_Float16)p.z; v[3] = (_Float16)p.w;
            v[4] = (_Float16)q.x; v[5] = (_Float16)q.y;
            v[6] = (_Float16)q.z; v[7] = (_Float16)q.w;
            af[t] = v;
        } else {
            h8 z;
            #pragma unroll
            for (int s = 0; s < 8; ++s) z[s] = (_Float16)0.f;
            af[t] = z;
        }
    }

    const _Float16* pL = wfL + (size_t)l * 8;
    const _Float16* pR = wfR + (size_t)l * 8;
    #pragma unroll 1
    for (int jt = 0; jt < 5; ++jt) {
        fx4 cl = {0.f, 0.f, 0.f, 0.f};
        fx4 cr = {0.f, 0.f, 0.f, 0.f};
        #pragma unroll
        for (int t = 0; t < KT; ++t) {
            const h8 bl_ = *(const h8*)(pL + (size_t)(jt * KT + t) * 512);
            const h8 br_ = *(const h8*)(pR + (size_t)(jt * KT + t) * 512);
            cl = __builtin_amdgcn_mfma_f32_16x16x32_f16(af[t], bl_, cl, 0, 0, 0);
            cr = __builtin_amdgcn_mfma_f32_16x16x32_f16(af[t], br_, cr, 0, 0, 0);
        }
        const int j0 = jt * 16;
        const float blv = bL[j0 + col];
        const float brv = bR[j0 + col];
        #pragma unroll
        for (int i = 0; i < 4; ++i) {
            const int nn = n0 + kg * 4 + i;
            outL16[(size_t)nn * HC + j0 + col] = F2US(cl[i] + blv);
            outR [(size_t)nn * HC + j0 + col] = cr[i] + brv;
        }
    }
}

// fallback transform (workspace too small): f32 compute, xl16/xr outputs
template<int DIN>
__global__ __launch_bounds__(320) void k_xform2(
    const float* __restrict__ A,
    const float* __restrict__ WL, const float* __restrict__ bL,
    const float* __restrict__ WR, const float* __restrict__ bR,
    unsigned short* __restrict__ outL16, float* __restrict__ outR, int nn) {
    __shared__ float As[16][68];
    __shared__ float WsL[16][80];
    __shared__ float WsR[16][80];
    const int t  = threadIdx.x;
    const int n0 = blockIdx.x * 64;
    const int tn = (t & 15) * 4;
    const int tj = (t >> 4) * 4;
    float4 accL[4], accR[4];
    #pragma unroll
    for (int u = 0; u < 4; ++u) {
        accL[u] = make_float4(0.f, 0.f, 0.f, 0.f);
        accR[u] = make_float4(0.f, 0.f, 0.f, 0.f);
    }
    for (int k0 = 0; k0 < DIN; k0 += 16) {
        __syncthreads();
        for (int i = t; i < 64*16; i += 320) {
            int nl = i >> 4, kk = i & 15;
            int n = n0 + nl;
            As[kk][nl] = (n < nn) ? A[(size_t)n*DIN + k0 + kk] : 0.f;
        }
        for (int i = t; i < 80*16; i += 320) {
            int jj = i >> 4, kk = i & 15;
            WsL[kk][jj] = WL[(size_t)jj*DIN + k0 + kk];
            WsR[kk][jj] = WR[(size_t)jj*DIN + k0 + kk];
        }
        __syncthreads();
        #pragma unroll
        for (int k = 0; k < 16; ++k) {
            const float4 av = *(const float4*)&As[k][tn];
            const float4 wl = *(const float4*)&WsL[k][tj];
            const float4 wr = *(const float4*)&WsR[k][tj];
            accL[0].x += av.x*wl.x; accL[0].y += av.x*wl.y; accL[0].z += av.x*wl.z; accL[0].w += av.x*wl.w;
            accL[1].x += av.y*wl.x; accL[1].y += av.y*wl.y; accL[1].z += av.y*wl.z; accL[1].w += av.y*wl.w;
            accL[2].x += av.z*wl.x; accL[2].y += av.z*wl.y; accL[2].z += av.z*wl.z; accL[2].w += av.z*wl.w;
            accL[3].x += av.w*wl.x; accL[3].y += av.w*wl.y; accL[3].z += av.w*wl.z; accL[3].w += av.w*wl.w;
            accR[0].x += av.x*wr.x; accR[0].y += av.x*wr.y; accR[0].z += av.x*wr.z; accR[0].w += av.x*wr.w;
            accR[1].x += av.y*wr.x; accR[1].y += av.y*wr.y; accR[1].z += av.y*wr.z; accR[1].w += av.y*wr.w;
            accR[2].x += av.z*wr.x; accR[2].y += av.z*wr.y; accR[2].z += av.z*wr.z; accR[2].w += av.z*wr.w;
            accR[3].x += av.w*wr.x; accR[3].y += av.w*wr.y; accR[3].z += av.w*wr.z; accR[3].w += av.w*wr.w;
        }
    }
    const float4 bvL = *(const float4*)(bL + tj);
    const float4 bvR = *(const float4*)(bR + tj);
    #pragma unroll
    for (int u = 0; u < 4; ++u) {
        int n = n0 + tn + u;
        if (n < nn) {
            const float ox = accL[u].x + bvL.x, oy = accL[u].y + bvL.y;
            const float oz = accL[u].z + bvL.z, ow = accL[u].w + bvL.w;
            int2 p;
            p.x = (int)F2US(ox) | ((int)F2US(oy) << 16);
            p.y = (int)F2US(oz) | ((int)F2US(ow) << 16);
            *(int2*)(outL16 + (size_t)n*HC + tj) = p;
            float4 o;
            o.x = accR[u].x + bvR.x; o.y = accR[u].y + bvR.y;
            o.z = accR[u].z + bvR.z; o.w = accR[u].w + bvR.w;
            *(float4*)(outR + (size_t)n*HC + tj) = o;
        }
    }
}

// cross-lane helpers.
// BCH: compile-time ds_swizzle broadcast of a half2 word (DS pipe):
//   imm = (j<<5)|0x10 -> lane i reads lane (i&0x10)|j, i.e. each 16-lane row
//   gets pair j held by its own lane j. j in 0..7 covers the 16 f16 values.
#define BCH(bits, j) __builtin_bit_cast(h2, \
    __builtin_amdgcn_ds_swizzle((bits), ((j) << 5) | 0x10))

// DPP rotate within each 16-lane row: pure VALU cross-lane, short latency.
// ctrl: 0x121 = row_ror:1, 0x122 = row_ror:2, 0x124 = row_ror:4, 0x128 = row_ror:8
template<int CTRL>
__device__ __forceinline__ float dpp_ror(float v) {
    return __int_as_float(__builtin_amdgcn_update_dpp(
        0, __float_as_int(v), CTRL, 0xF, 0xF, true));
}

// per-edge logit+exp+accumulate, no gate (tail is peeled by the caller):
//   em via 8 ds_swizzle half2 broadcasts + 2 chains of 4 fdot2 (f32 accum,
//   seeded with xlv+xrc); leaky; att scale; 16-lane row-sum via 4 DPP
//   rotate-adds; exp; accumulate.
__device__ __forceinline__ void edge_step10(
    int eab, float xlv, float xrc, float attc,
    h2 wp0, h2 wp1, h2 wp2, h2 wp3, h2 wp4, h2 wp5, h2 wp6, h2 wp7,
    float& acc, float& l) {
    float a = FDOT2(wp3, BCH(eab, 3),
              FDOT2(wp2, BCH(eab, 2),
              FDOT2(wp1, BCH(eab, 1),
              FDOT2(wp0, BCH(eab, 0), xlv + xrc))));
    float b = FDOT2(wp7, BCH(eab, 7),
              FDOT2(wp6, BCH(eab, 6),
              FDOT2(wp5, BCH(eab, 5),
              FDOT2(wp4, BCH(eab, 4), 0.f))));
    float v = a + b;
    v = fmaxf(v, 0.f) + NEG_SLOPE * fminf(v, 0.f);
    v *= attc;
    v += dpp_ror<0x121>(v);
    v += dpp_ror<0x122>(v);
    v += dpp_ror<0x124>(v);
    v += dpp_ror<0x128>(v);
    const float pt = __expf(v);
    acc = __fmaf_rn(pt, xlv, acc);
    l  += pt;
}

// ====== fused attention v11 (sorted path): 1 node per 80-thread group =======
// 4 edges/iter, gate-free main loop + statically-indexed predicated tail.
// xl is an f16 table (rows 160B): the random per-edge gather is
// L2-miss-line-rate bound, so smaller rows = fewer miss bytes.
__global__ __launch_bounds__(320) void k_fused11(
    const unsigned short* __restrict__ xl16, const float* __restrict__ xr,
    const int* __restrict__ eh,    // CSR-ordered f16-pair rows (8 ints/edge)
    const float* __restrict__ we, const float* __restrict__ att,
    const int* __restrict__ src_s,
    const int* __restrict__ rowstart, const int* __restrict__ nodeord,
    const float* __restrict__ bias, float* __restrict__ out, int relu) {
    const int t = threadIdx.x;
    const int group = t / 80;
    const int c = t - group * 80;
    const int idx = blockIdx.x * 4 + group;
    if (idx >= N_NODES) return;
    const int n = nodeord[idx];
    const int pj = c & 7;

    // weights as 8 half2 pairs (f16 rounding; verified harmless in v9)
    const float4* w4 = (const float4*)(we + c * ED_DIM);
    const float4 wa = w4[0], wb = w4[1], wc = w4[2], wd = w4[3];
    const h2 wp0 = PKH2(wa.x, wa.y), wp1 = PKH2(wa.z, wa.w);
    const h2 wp2 = PKH2(wb.x, wb.y), wp3 = PKH2(wb.z, wb.w);
    const h2 wp4 = PKH2(wc.x, wc.y), wp5 = PKH2(wc.z, wc.w);
    const h2 wp6 = PKH2(wd.x, wd.y), wp7 = PKH2(wd.z, wd.w);

    const float attc = att[c];
    const float bc   = bias[c];
    const float xrc  = xr[n * HC + c];

    const int rs = rowstart[n], re = rowstart[n + 1];
    float l = 0.f, acc = 0.f;

    if (rs < re) {
        const unsigned short* xlc = xl16 + c;        // per-lane base
        const int*   sp  = src_s + rs;
        const int*   ep  = eh + (size_t)rs * 8 + pj;

        // preamble: xl+ea values for quad 0 in flight; offsets for quad 1
        const int o0 = sp[0], o1 = sp[1], o2 = sp[2], o3 = sp[3];
        int n0 = sp[4], n1 = sp[5], n2 = sp[6], n3 = sp[7];
        sp += 8;
        float xA = US2F(xlc[o0]), xB = US2F(xlc[o1]);
        float xC = US2F(xlc[o2]), xD = US2F(xlc[o3]);
        int eA = ep[0], eB = ep[8], eC = ep[16], eD = ep[24];
        ep += 32;

        const int nq = (re - rs) >> 2;
        for (int q = 0; q < nq; ++q) {
            const float x0 = xA, x1 = xB, x2 = xC, x3 = xD;
            const int   e0 = eA, e1 = eB, e2 = eC, e3 = eD;
            // issue next-quad loads; offsets were fetched last iteration
            xA = US2F(xlc[n0]); xB = US2F(xlc[n1]);
            xC = US2F(xlc[n2]); xD = US2F(xlc[n3]);
            n0 = sp[0]; n1 = sp[1]; n2 = sp[2]; n3 = sp[3];
            sp += 4;
            eA = ep[0]; eB = ep[8]; eC = ep[16]; eD = ep[24];
            ep += 32;

            edge_step10(e0, x0, xrc, attc, wp0,wp1,wp2,wp3,wp4,wp5,wp6,wp7, acc, l);
            edge_step10(e1, x1, xrc, attc, wp0,wp1,wp2,wp3,wp4,wp5,wp6,wp7, acc, l);
            edge_step10(e2, x2, xrc, attc, wp0,wp1,wp2,wp3,wp4,wp5,wp6,wp7, acc, l);
            edge_step10(e3, x3, xrc, attc, wp0,wp1,wp2,wp3,wp4,wp5,wp6,wp7, acc, l);
        }
        // tail: 0..3 edges, values already in (xA,eA)..(xC,eC)
        const int tl = (re - rs) & 3;
        if (tl > 0) edge_step10(eA, xA, xrc, attc, wp0,wp1,wp2,wp3,wp4,wp5,wp6,wp7, acc, l);
        if (tl > 1) edge_step10(eB, xB, xrc, attc, wp0,wp1,wp2,wp3,wp4,wp5,wp6,wp7, acc, l);
        if (tl > 2) edge_step10(eC, xC, xrc, attc, wp0,wp1,wp2,wp3,wp4,wp5,wp6,wp7, acc, l);
    }
    float o = acc / (l + 1e-16f) + bc;
    if (relu) o = fmaxf(o, 0.f);
    out[n * HC + c] = o;
}

// fallback (workspace too small for eattr_h): gated 2-edge loop, f16 xl
__global__ __launch_bounds__(320) void k_fused_nb(
    const unsigned short* __restrict__ xl16, const float* __restrict__ xr,
    const float* __restrict__ ef,
    const float* __restrict__ we, const float* __restrict__ att,
    const int* __restrict__ perm, const int* __restrict__ src_s,
    const int* __restrict__ rowstart, const int* __restrict__ nodeord,
    const float* __restrict__ bias, float* __restrict__ out, int relu) {
    const int t = threadIdx.x;
    const int group = t / 80;
    const int c = t - group * 80;
    const int idx = blockIdx.x * 4 + group;
    if (idx >= N_NODES) return;
    const int n = nodeord[idx];
    const int pj = c & 7;

    const float4* w4 = (const float4*)(we + c * ED_DIM);
    const float4 wa = w4[0], wb = w4[1], wc = w4[2], wd = w4[3];
    const h2 wp0 = PKH2(wa.x, wa.y), wp1 = PKH2(wa.z, wa.w);
    const h2 wp2 = PKH2(wb.x, wb.y), wp3 = PKH2(wb.z, wb.w);
    const h2 wp4 = PKH2(wc.x, wc.y), wp5 = PKH2(wc.z, wc.w);
    const h2 wp6 = PKH2(wd.x, wd.y), wp7 = PKH2(wd.z, wd.w);

    const float attc = att[c];
    const float bc   = bias[c];
    const float xrc  = xr[n * HC + c];

    const int rs = rowstart[n], re = rowstart[n + 1];
    float l = 0.f, acc = 0.f;

    if (rs < re) {
        const int o0 = src_s[rs];
        const int o1 = src_s[rs + 1];
        int sA = src_s[rs + 2];
        int sB = src_s[rs + 3];
        float xlA = US2F(xl16[o0 + c]);
        float xlB = US2F(xl16[o1 + c]);
        const int e0i = perm[rs], e1i = perm[rs + 1];
        const float2 f0 = *(const float2*)(ef + (size_t)e0i * ED_DIM + 2 * pj);
        const float2 f1 = *(const float2*)(ef + (size_t)e1i * ED_DIM + 2 * pj);
        int eaA = __builtin_bit_cast(int, PKH2(f0.x, f0.y));
        int eaB = __builtin_bit_cast(int, PKH2(f1.x, f1.y));

        for (int p = rs; p < re; p += 2) {
            const float xl0 = xlA, xl1 = xlB;
            const int ea0 = eaA, ea1 = eaB;
            xlA = US2F(xl16[sA + c]);
            xlB = US2F(xl16[sB + c]);
            sA = src_s[p + 4];
            sB = src_s[p + 5];
            const int en0 = perm[p + 2], en1 = perm[p + 3];
            const float2 g0 = *(const float2*)(ef + (size_t)en0 * ED_DIM + 2 * pj);
            const float2 g1 = *(const float2*)(ef + (size_t)en1 * ED_DIM + 2 * pj);
            eaA = __builtin_bit_cast(int, PKH2(g0.x, g0.y));
            eaB = __builtin_bit_cast(int, PKH2(g1.x, g1.y));

            float acc0 = 0.f, l0 = 0.f;
            edge_step10(ea0, xl0, xrc, attc, wp0,wp1,wp2,wp3,wp4,wp5,wp6,wp7, acc0, l0);
            acc += acc0; l += l0;
            if (p + 1 < re) {
                edge_step10(ea1, xl1, xrc, attc, wp0,wp1,wp2,wp3,wp4,wp5,wp6,wp7, acc, l);
            }
        }
    }
    float o = acc / (l + 1e-16f) + bc;
    if (relu) o = fmaxf(o, 0.f);
    out[n * HC + c] = o;
}

extern "C" void kernel_launch(void* const* d_in, const int* in_sizes, int n_in,
                              void* d_out, int out_size, void* d_ws, size_t ws_size,
                              hipStream_t stream) {
    (void)in_sizes; (void)n_in; (void)out_size;
    const float* x     = (const float*)d_in[0];
    const int*   ei    = (const int*)d_in[1];
    const float* eattr = (const float*)d_in[2];
    const int* srcp = ei;
    const int* dstp = ei + N_EDGES;

    // workspace layout
    float* h      = (float*)d_ws;                            // N*80 f32
    unsigned short* xl16 = (unsigned short*)(h + (size_t)N_NODES*HC); // N*80 f16
    float* xr     = (float*)(xl16 + (size_t)N_NODES*HC);     // N*80 f32
    int* rowstart = (int*)(xr + (size_t)N_NODES*HC);         // N+1
    int* cursor   = rowstart + (N_NODES + 1);                // N
    int* perm     = cursor + N_NODES;                        // E + EPAD
    int* src_s    = perm + N_EDGES + EPAD;                   // E + EPAD
    int* partial  = src_s + N_EDGES + EPAD;                  // SCAN_G
    int* blockoff = partial + SCAN_G;                        // SCAN_G
    int* dhist    = blockoff + SCAN_G;                       // DBIN
    int* dcur     = dhist + DBIN;                            // DBIN
    int* nodeord  = dcur + DBIN;                             // N
    // 64B-align eattr_h: rows are 32B (8 half2 words), written with int4 pairs
    int* eattr_h = (int*)(((uintptr_t)(nodeord + N_NODES) + 63) &
                          ~(uintptr_t)63);                   // (E+16)*8 ints
    // 64B-align wbuf: 100 fragments x 1KB of pre-packed f16 weights
    _Float16* wbuf = (_Float16*)(((uintptr_t)(eattr_h + (size_t)(N_EDGES + EPAD) * 8)
                                  + 63) & ~(uintptr_t)63);
    float* outp   = (float*)d_out;

    const size_t need_sorted =
        (size_t)((char*)(wbuf + 100 * 512) - (char*)d_ws);
    const bool use_sorted = (ws_size >= need_sorted);

    const dim3 gf((N_NODES + 3) / 4);
    const dim3 gx2((N_NODES + 63) / 64);
    const dim3 geb((N_EDGES + 255) / 256);
    const dim3 gnb((N_NODES + 255) / 256);

    // ---- build CSR by destination + degree-sorted node order (once) ----
    hipMemsetAsync(cursor, 0, (size_t)N_NODES * sizeof(int), stream);
    k_hist<<<geb, 256, 0, stream>>>(dstp, cursor, dhist);
    k_part<<<SCAN_G, SCAN_B, 0, stream>>>(cursor, partial);
    k_scanp<<<1, 512, 0, stream>>>(partial, blockoff, rowstart);
    k_apply<<<SCAN_G, SCAN_B, 0, stream>>>(cursor, blockoff, rowstart, dhist);
    k_degoff<<<1, 64, 0, stream>>>(dhist, dcur, perm, src_s);
    k_degplace<<<gnb, 256, 0, stream>>>(rowstart, dcur, nodeord);
    if (use_sorted) {
        k_place<true><<<geb, 256, 0, stream>>>(srcp, dstp, rowstart, cursor,
                                               perm, src_s, eattr, eattr_h);
        k_wpack<<<100, 64, 0, stream>>>((const float*)d_in[3], (const float*)d_in[5],
                                        (const float*)d_in[10], (const float*)d_in[12],
                                        (const float*)d_in[17], (const float*)d_in[19],
                                        wbuf);
    } else {
        k_place<false><<<geb, 256, 0, stream>>>(srcp, dstp, rowstart, cursor,
                                                perm, src_s, eattr, eattr_h);
    }

    for (int L = 0; L < 3; ++L) {
        const float* in   = (L == 0) ? x : h;
        float*       oacc = (L == 2) ? outp : h;
        const float* wl   = (const float*)d_in[3 + L*7 + 0];
        const float* bl   = (const float*)d_in[3 + L*7 + 1];
        const float* wr   = (const float*)d_in[3 + L*7 + 2];
        const float* br   = (const float*)d_in[3 + L*7 + 3];
        const float* we   = (const float*)d_in[3 + L*7 + 4];
        const float* att  = (const float*)d_in[3 + L*7 + 5];
        const float* bias = (const float*)d_in[3 + L*7 + 6];

        if (use_sorted) {
            const _Float16* wfL = (L == 0) ? wbuf
                                : (L == 1) ? wbuf + (size_t)40 * 512
                                           : wbuf + (size_t)70 * 512;
            const _Float16* wfR = (L == 0) ? wbuf + (size_t)20 * 512
                                : (L == 1) ? wbuf + (size_t)55 * 512
                                           : wbuf + (size_t)85 * 512;
            if (L == 0) {
                k_xform2f<F_IN><<<gx2, 256, 0, stream>>>(in, wfL, wfR, bl, br, xl16, xr);
            } else {
                k_xform2f<HC><<<gx2, 256, 0, stream>>>(in, wfL, wfR, bl, br, xl16, xr);
            }
            k_fused11<<<gf, 320, 0, stream>>>(xl16, xr, eattr_h, we, att,
                                              src_s, rowstart, nodeord, bias,
                                              oacc, (L < 2) ? 1 : 0);
        } else {
            if (L == 0) {
                k_xform2<F_IN><<<gx2, 320, 0, stream>>>(in, wl, bl, wr, br, xl16, xr, N_NODES);
            } else {
                k_xform2<HC><<<gx2, 320, 0, stream>>>(in, wl, bl, wr, br, xl16, xr, N_NODES);
            }
            k_fused_nb<<<gf, 320, 0, stream>>>(xl16, xr, eattr, we, att, perm,
                                               src_s, rowstart, nodeord, bias,
                                               oacc, (L < 2) ? 1 : 0);
        }
    }
}